// Round 9
// baseline (237.374 us; speedup 1.0000x reference)
//
#include <hip/hip_runtime.h>

#define DM 128
#define DFF 512
#define CLAMP_V 5.0f
#define LN_EPS 1e-5f

typedef __attribute__((ext_vector_type(8))) short bf16x8;
typedef __attribute__((ext_vector_type(4))) float f32x4;

__device__ __forceinline__ float b2f(ushort u) {
  union { uint u; float f; } x; x.u = ((uint)u) << 16; return x.f;
}
__device__ __forceinline__ ushort f2b(float f) {
  union { float f; uint u; } x; x.f = f;
  uint r = x.u + 0x7FFFu + ((x.u >> 16) & 1u);
  return (ushort)(r >> 16);
}
__device__ __forceinline__ void unpackw(uint w, float& lo, float& hi) {
  union { uint u; float f; } A, B;
  A.u = w << 16; B.u = w & 0xFFFF0000u;
  lo = A.f; hi = B.f;
}
__device__ __forceinline__ void unpack8w(uint4 w, float* o) {
  unpackw(w.x, o[0], o[1]); unpackw(w.y, o[2], o[3]);
  unpackw(w.z, o[4], o[5]); unpackw(w.w, o[6], o[7]);
}

// ---------------- fused cast: feat (vectorized) + all weights ----------------
__global__ void k_castall(const float* __restrict__ feat,
                          const float* __restrict__ wq, const float* __restrict__ wk,
                          const float* __restrict__ wv, const float* __restrict__ wo,
                          const float* __restrict__ w1, const float* __restrict__ w2,
                          ushort* __restrict__ feat_bf, ushort* __restrict__ wbf,
                          int nf4) {
  int i = blockIdx.x * blockDim.x + threadIdx.x;
  if (i < nf4) {
    float4 v = *reinterpret_cast<const float4*>(feat + i * 4);
    ushort4 o; o.x = f2b(v.x); o.y = f2b(v.y); o.z = f2b(v.z); o.w = f2b(v.w);
    *reinterpret_cast<ushort4*>(feat_bf + i * 4) = o;
    return;
  }
  int i4 = (i - nf4) * 4;
  if (i4 >= 196608) return;
  const float* s; int o;
  if      (i4 < 16384)  { s = wq; o = i4; }
  else if (i4 < 32768)  { s = wk; o = i4 - 16384; }
  else if (i4 < 49152)  { s = wv; o = i4 - 32768; }
  else if (i4 < 65536)  { s = wo; o = i4 - 49152; }
  else if (i4 < 131072) { s = w1; o = i4 - 65536; }
  else                  { s = w2; o = i4 - 131072; }
  float4 v = *reinterpret_cast<const float4*>(s + o);
  ushort4 u; u.x = f2b(v.x); u.y = f2b(v.y); u.z = f2b(v.z); u.w = f2b(v.w);
  *reinterpret_cast<ushort4*>(wbf + i4) = u;
}

// ---------------- CSR build ----------------
__global__ void k_count(const int* __restrict__ dst, int* __restrict__ deg, int E) {
  int e = blockIdx.x * blockDim.x + threadIdx.x;
  if (e < E) atomicAdd(&deg[dst[e]], 1);
}

#define SC_EPB 1024

__global__ __launch_bounds__(256) void k_scan1(const int* __restrict__ deg,
                                               int* __restrict__ off,
                                               int* __restrict__ bsum, int n) {
  __shared__ int sh[256];
  const int t = threadIdx.x;
  int base = blockIdx.x * SC_EPB + t * 4;
  int4 v = {0, 0, 0, 0};
  if (base + 3 < n) {
    v = *reinterpret_cast<const int4*>(deg + base);
  } else {
    if (base     < n) v.x = deg[base];
    if (base + 1 < n) v.y = deg[base + 1];
    if (base + 2 < n) v.z = deg[base + 2];
    if (base + 3 < n) v.w = deg[base + 3];
  }
  int s = v.x + v.y + v.z + v.w;
  sh[t] = s;
  __syncthreads();
  #pragma unroll
  for (int d = 1; d < 256; d <<= 1) {
    int x = 0;
    if (t >= d) x = sh[t - d];
    __syncthreads();
    sh[t] += x;
    __syncthreads();
  }
  int ex = sh[t] - s;
  if (base + 3 < n) {
    int4 o; o.x = ex; o.y = ex + v.x; o.z = ex + v.x + v.y; o.w = ex + v.x + v.y + v.z;
    *reinterpret_cast<int4*>(off + base) = o;
  } else {
    if (base     < n) off[base]     = ex;
    if (base + 1 < n) off[base + 1] = ex + v.x;
    if (base + 2 < n) off[base + 2] = ex + v.x + v.y;
    if (base + 3 < n) off[base + 3] = ex + v.x + v.y + v.z;
  }
  if (t == 255) bsum[blockIdx.x] = sh[255];
}

// scan3 with inlined block-sum prefix (wave-parallel over <=64 block sums)
__global__ __launch_bounds__(256) void k_scan3(int* __restrict__ off,
                                               const int* __restrict__ bsum,
                                               int nbk, int n, int E) {
  __shared__ int sadd;
  const int t = threadIdx.x;
  if (t < 64) {
    int v = (t < nbk && t < (int)blockIdx.x) ? bsum[t] : 0;
    #pragma unroll
    for (int msk = 1; msk < 64; msk <<= 1) v += __shfl_xor(v, msk);
    if (t == 0) sadd = v;
  }
  __syncthreads();
  int add = sadd;
  int base = blockIdx.x * SC_EPB + t * 4;
  if (base + 3 < n) {
    int4 v = *reinterpret_cast<int4*>(off + base);
    v.x += add; v.y += add; v.z += add; v.w += add;
    *reinterpret_cast<int4*>(off + base) = v;
  } else {
    if (base     < n) off[base]     += add;
    if (base + 1 < n) off[base + 1] += add;
    if (base + 2 < n) off[base + 2] += add;
  }
  if (blockIdx.x == 0 && t == 0) off[n] = E;
}

__global__ void k_scatter(const int* __restrict__ src, const int* __restrict__ dst,
                          const int* __restrict__ off, int* __restrict__ cur,
                          int* __restrict__ csr, int E) {
  int e = blockIdx.x * blockDim.x + threadIdx.x;
  if (e < E) {
    int d = dst[e];
    int p = off[d] + atomicAdd(&cur[d], 1);
    csr[p] = src[e];
  }
}

// =====================================================================
// k_mmR: register GEMM, no LDS staging. A,W read directly (L2/L3-hot).
// Block = 4 waves (2x2 of 64x64), block tile 128 x 128. K = 128 or 512.
// MFMA fragment = plain row-major 16B chunk: lane ln reads
// row (ln&15), k-chunk (ln>>4). FLAGS: 1=bias 2=relu 4=res 8=LN(gridx==1)
// =====================================================================
template<int FLAGS, bool QKVSPLIT, bool OUTF, bool OUTB>
__global__ __launch_bounds__(256) void k_mmR(
    const ushort* __restrict__ A, const ushort* __restrict__ W,
    const float* __restrict__ bias, const float* __restrict__ res,
    const float* __restrict__ lng, const float* __restrict__ lnbv,
    float* __restrict__ Cf, ushort* __restrict__ Cb, ushort* __restrict__ Cb2,
    int M, int K, int NO)
{
  __shared__ float lnred[(FLAGS & 8) ? 512 : 4];
  const int tid = threadIdx.x;
  const int wv = tid >> 6, ln = tid & 63;
  const int bnb = blockIdx.x;
  const int mbase = blockIdx.y * 128;
  const int wrow = (wv >> 1) * 64, wcol = (wv & 1) * 64;
  const int lr = ln & 15;
  const int lc = (ln >> 4) * 8;

  const ushort* Ab[4];
  const ushort* Wb[4];
  #pragma unroll
  for (int m = 0; m < 4; ++m) {
    int gr = min(mbase + wrow + m * 16 + lr, M - 1);
    Ab[m] = A + (size_t)gr * K + lc;
  }
  #pragma unroll
  for (int n = 0; n < 4; ++n) {
    int gc = bnb * 128 + wcol + n * 16 + lr;
    Wb[n] = W + (size_t)gc * K + lc;
  }

  f32x4 acc[4][4] = {};
  for (int k0 = 0; k0 < K; k0 += 32) {
    bf16x8 af[4], bf[4];
    #pragma unroll
    for (int m = 0; m < 4; ++m) af[m] = *reinterpret_cast<const bf16x8*>(Ab[m] + k0);
    #pragma unroll
    for (int n = 0; n < 4; ++n) bf[n] = *reinterpret_cast<const bf16x8*>(Wb[n] + k0);
    #pragma unroll
    for (int m = 0; m < 4; ++m)
      #pragma unroll
      for (int n = 0; n < 4; ++n)
        acc[m][n] = __builtin_amdgcn_mfma_f32_16x16x32_bf16(af[m], bf[n], acc[m][n], 0, 0, 0);
  }

  if constexpr ((FLAGS & 8) != 0) {
    // ---- fused register-space LN epilogue (gridDim.x == 1, 128 cols) ----
    #pragma unroll
    for (int m = 0; m < 4; ++m)
      #pragma unroll
      for (int n = 0; n < 4; ++n) {
        int gc = wcol + n * 16 + lr;
        float bsv = (FLAGS & 1) ? bias[gc] : 0.f;
        #pragma unroll
        for (int r = 0; r < 4; ++r) {
          int gr = mbase + wrow + m * 16 + (ln >> 4) * 4 + r;
          float v = acc[m][n][r] + bsv;
          if (FLAGS & 2) v = fmaxf(v, 0.f);
          if (FLAGS & 4) v += res[(size_t)min(gr, M - 1) * 128 + gc];
          acc[m][n][r] = v;
        }
      }
    #pragma unroll
    for (int m = 0; m < 4; ++m)
      #pragma unroll
      for (int r = 0; r < 4; ++r) {
        float sm = acc[m][0][r] + acc[m][1][r] + acc[m][2][r] + acc[m][3][r];
        float sq = acc[m][0][r] * acc[m][0][r] + acc[m][1][r] * acc[m][1][r]
                 + acc[m][2][r] * acc[m][2][r] + acc[m][3][r] * acc[m][3][r];
        #pragma unroll
        for (int msk = 1; msk <= 8; msk <<= 1) {
          sm += __shfl_xor(sm, msk);
          sq += __shfl_xor(sq, msk);
        }
        if (lr == 0) {
          int row = wrow + m * 16 + (ln >> 4) * 4 + r;
          lnred[row * 4 + (wv & 1) * 2]     = sm;
          lnred[row * 4 + (wv & 1) * 2 + 1] = sq;
        }
      }
    __syncthreads();
    #pragma unroll
    for (int m = 0; m < 4; ++m)
      #pragma unroll
      for (int r = 0; r < 4; ++r) {
        int row = wrow + m * 16 + (ln >> 4) * 4 + r;
        int gr = mbase + row;
        float sm = lnred[row * 4] + lnred[row * 4 + 2];
        float sq = lnred[row * 4 + 1] + lnred[row * 4 + 3];
        float mu = sm * (1.f / 128.f);
        float var = fmaxf(sq * (1.f / 128.f) - mu * mu, 0.f);
        float rstd = rsqrtf(var + LN_EPS);
        if (gr < M) {
          #pragma unroll
          for (int n = 0; n < 4; ++n) {
            int gc = wcol + n * 16 + lr;
            float y = (acc[m][n][r] - mu) * rstd * lng[gc] + lnbv[gc];
            if (OUTF) Cf[(size_t)gr * 128 + gc] = y;
            if (OUTB) Cb[(size_t)gr * 128 + gc] = f2b(y);
          }
        }
      }
  } else {
    #pragma unroll
    for (int m = 0; m < 4; ++m) {
      int gr0 = mbase + wrow + m * 16 + (ln >> 4) * 4;
      #pragma unroll
      for (int n = 0; n < 4; ++n) {
        int gcl = wcol + n * 16 + lr;
        float bsv = (FLAGS & 1) ? bias[bnb * 128 + gcl] : 0.f;
        #pragma unroll
        for (int r = 0; r < 4; ++r) {
          int gr = gr0 + r;
          if (gr >= M) continue;
          float v = acc[m][n][r] + bsv;
          if (FLAGS & 2) v = fmaxf(v, 0.f);
          if (FLAGS & 4) v += res[(size_t)gr * NO + bnb * 128 + gcl];
          if (QKVSPLIT) {
            if (bnb == 0) Cb[(size_t)gr * 128 + gcl] = f2b(v);
            else          Cb2[(size_t)gr * 256 + (bnb - 1) * 128 + gcl] = f2b(v);
          } else {
            if (OUTF) Cf[(size_t)gr * NO + bnb * 128 + gcl] = v;
            if (OUTB) Cb[(size_t)gr * NO + bnb * 128 + gcl] = f2b(v);
          }
        }
      }
    }
  }
}

// ---------------- edge-softmax attention (round-7 version: fixed-max) ----
// 8 groups x 8 lanes, lane = full head; single prefetch of next edge id.
__global__ __launch_bounds__(256) void k_attn(
    const ushort* __restrict__ q, const ushort* __restrict__ kv,
    const int* __restrict__ off, const int* __restrict__ csr,
    ushort* __restrict__ sav, int n)
{
  int node = blockIdx.x * 4 + (threadIdx.x >> 6);
  int lane = threadIdx.x & 63;
  if (node >= n) return;
  const int g = lane >> 3, sl = lane & 7;

  const ushort* qr = q + (size_t)node * 128 + sl * 16;
  uint4 qw0 = *reinterpret_cast<const uint4*>(qr);
  uint4 qw1 = *reinterpret_cast<const uint4*>(qr + 8);
  float qv[16];
  unpack8w(qw0, qv); unpack8w(qw1, qv + 8);

  int b = off[node], e = off[node + 1];
  float s = 0.f;
  float a[16] = {};
  int nIt = (e - b + 7) >> 3;
  int idx = b + g;
  int sn = (b < e) ? csr[min(idx, e - 1)] : 0;

  for (int i = 0; i < nIt; ++i) {
    bool act = idx < e;
    const ushort* kr = kv + (size_t)sn * 256 + sl * 16;
    uint4 kw0 = *reinterpret_cast<const uint4*>(kr);
    uint4 kw1 = *reinterpret_cast<const uint4*>(kr + 8);
    uint4 vw0 = *reinterpret_cast<const uint4*>(kr + 128);
    uint4 vw1 = *reinterpret_cast<const uint4*>(kr + 136);
    idx += 8;
    if (i + 1 < nIt) sn = csr[min(idx, e - 1)];

    float kk[16];
    unpack8w(kw0, kk); unpack8w(kw1, kk + 8);
    float p = 0.f;
    #pragma unroll
    for (int j = 0; j < 16; ++j) p = fmaf(qv[j], kk[j], p);
    float u = fminf(fmaxf(p * 0.25f, -CLAMP_V), CLAMP_V);
    float w = __expf(u - CLAMP_V);
    w = act ? w : 0.f;
    s += w;
    float vvv[16];
    unpack8w(vw0, vvv); unpack8w(vw1, vvv + 8);
    #pragma unroll
    for (int j = 0; j < 16; ++j) a[j] = fmaf(w, vvv[j], a[j]);
  }

  #pragma unroll
  for (int msk = 8; msk <= 32; msk <<= 1) {
    s += __shfl_xor(s, msk);
    #pragma unroll
    for (int j = 0; j < 16; ++j) a[j] += __shfl_xor(a[j], msk);
  }

  float inv = (s > 0.f) ? 1.f / s : 0.f;
  if (g == 0) {
    uint w[8];
    #pragma unroll
    for (int j = 0; j < 8; ++j)
      w[j] = (uint)f2b(a[2 * j] * inv) | ((uint)f2b(a[2 * j + 1] * inv) << 16);
    ushort* outp = sav + (size_t)node * 128 + sl * 16;
    uint4 o0 = {w[0], w[1], w[2], w[3]};
    uint4 o1 = {w[4], w[5], w[6], w[7]};
    *reinterpret_cast<uint4*>(outp) = o0;
    *reinterpret_cast<uint4*>(outp + 8) = o1;
  }
}

extern "C" void kernel_launch(void* const* d_in, const int* in_sizes, int n_in,
                              void* d_out, int out_size, void* d_ws, size_t ws_size,
                              hipStream_t stream)
{
  const float* feat = (const float*)d_in[0];
  const int*   src  = (const int*)d_in[1];
  const int*   dst  = (const int*)d_in[2];
  const float* Wq   = (const float*)d_in[3];
  const float* Wk   = (const float*)d_in[4];
  const float* Wv   = (const float*)d_in[5];
  const float* Wo   = (const float*)d_in[6];
  const float* ln1g = (const float*)d_in[7];
  const float* ln1b = (const float*)d_in[8];
  const float* W1   = (const float*)d_in[9];
  const float* b1   = (const float*)d_in[10];
  const float* W2   = (const float*)d_in[11];
  const float* b2   = (const float*)d_in[12];
  const float* ln2g = (const float*)d_in[13];
  const float* ln2b = (const float*)d_in[14];
  float* out = (float*)d_out;

  const int N = in_sizes[0] / DM;
  const int E = in_sizes[1];
  const size_t NB = (size_t)N;

  char* wsb = (char*)d_ws;
  ushort* q_bf    = (ushort*)wsb;
  ushort* kv_bf   = (ushort*)(wsb + NB * 256);
  ushort* sav_bf  = (ushort*)(wsb + NB * 768);
  ushort* mid_bf  = (ushort*)wsb;
  float*  h1      = (float*)(wsb + NB * 1024);
  ushort* h1b     = (ushort*)(wsb + NB * 1536);
  ushort* feat_bf = (ushort*)(wsb + NB * 1792);
  ushort* wbf     = (ushort*)(wsb + NB * 2048);
  ushort* wqkv_bf = wbf;
  ushort* wo_bf   = wbf + 49152;
  ushort* w1_bf   = wbf + 65536;
  ushort* w2_bf   = wbf + 131072;
  int* ib  = (int*)(wbf + 196608);
  int* deg = ib;
  int* cur = ib + N;
  int* off = ib + 2 * N;
  int* csr = ib + 3 * N + 1;
  int* bsum = csr + E;

  hipMemsetAsync(deg, 0, 2 * (size_t)N * sizeof(int), stream);

  int nf4 = N * DM / 4;
  k_castall<<<(nf4 + 49152 + 255) / 256, 256, 0, stream>>>(
      feat, Wq, Wk, Wv, Wo, W1, W2, feat_bf, wbf, nf4);

  int eb = (E + 255) / 256;
  int nbk = (N + SC_EPB - 1) / SC_EPB;
  k_count<<<eb, 256, 0, stream>>>(dst, deg, E);
  k_scan1<<<nbk, 256, 0, stream>>>(deg, off, bsum, N);
  k_scan3<<<nbk, 256, 0, stream>>>(off, bsum, nbk, N, E);
  k_scatter<<<eb, 256, 0, stream>>>(src, dst, off, cur, csr, E);

  int nb4 = (N + 3) / 4;
  const int nT = (N + 127) / 128;   // 313

  // qkv: grid (3, nT), split output q_bf | kv_bf
  k_mmR<0, true, false, true><<<dim3(3, nT), 256, 0, stream>>>(
      feat_bf, wqkv_bf, nullptr, nullptr, nullptr, nullptr,
      nullptr, q_bf, kv_bf, N, DM, 384);

  k_attn<<<nb4, 256, 0, stream>>>(q_bf, kv_bf, off, csr, sav_bf, N);

  // h1 = LN1(sav @ Wo^T + feat) -> h1 f32 + h1b bf16
  k_mmR<4 | 8, false, true, true><<<dim3(1, nT), 256, 0, stream>>>(
      sav_bf, wo_bf, nullptr, feat, ln1g, ln1b, h1, h1b, nullptr, N, DM, DM);

  // mid = relu(h1 @ W1^T + b1)
  k_mmR<1 | 2, false, false, true><<<dim3(4, nT), 256, 0, stream>>>(
      h1b, w1_bf, b1, nullptr, nullptr, nullptr,
      nullptr, mid_bf, nullptr, N, DM, DFF);

  // out = LN2(mid @ W2^T + b2 + h1), K=512
  k_mmR<1 | 4 | 8, false, true, false><<<dim3(1, nT), 256, 0, stream>>>(
      mid_bf, w2_bf, b2, h1, ln2g, ln2b, out, nullptr, nullptr, N, DFF, DM);
}

// Round 10
// 195.765 us; speedup vs baseline: 1.2125x; 1.2125x over previous
//
#include <hip/hip_runtime.h>

#define DM 128
#define DFF 512
#define CLAMP_V 5.0f
#define LN_EPS 1e-5f

typedef __attribute__((ext_vector_type(8))) short bf16x8;
typedef __attribute__((ext_vector_type(4))) float f32x4;

__device__ __forceinline__ float b2f(ushort u) {
  union { uint u; float f; } x; x.u = ((uint)u) << 16; return x.f;
}
__device__ __forceinline__ ushort f2b(float f) {
  union { float f; uint u; } x; x.f = f;
  uint r = x.u + 0x7FFFu + ((x.u >> 16) & 1u);
  return (ushort)(r >> 16);
}
__device__ __forceinline__ void unpackw(uint w, float& lo, float& hi) {
  union { uint u; float f; } A, B;
  A.u = w << 16; B.u = w & 0xFFFF0000u;
  lo = A.f; hi = B.f;
}
__device__ __forceinline__ void unpack8w(uint4 w, float* o) {
  unpackw(w.x, o[0], o[1]); unpackw(w.y, o[2], o[3]);
  unpackw(w.z, o[4], o[5]); unpackw(w.w, o[6], o[7]);
}

// ---------------- fused cast: feat + all weights ----------------
__global__ void k_castall(const float* __restrict__ feat,
                          const float* __restrict__ wq, const float* __restrict__ wk,
                          const float* __restrict__ wv, const float* __restrict__ wo,
                          const float* __restrict__ w1, const float* __restrict__ w2,
                          ushort* __restrict__ feat_bf, ushort* __restrict__ wbf,
                          int nf4) {
  int i = blockIdx.x * blockDim.x + threadIdx.x;
  if (i < nf4) {
    float4 v = *reinterpret_cast<const float4*>(feat + i * 4);
    ushort4 o; o.x = f2b(v.x); o.y = f2b(v.y); o.z = f2b(v.z); o.w = f2b(v.w);
    *reinterpret_cast<ushort4*>(feat_bf + i * 4) = o;
    return;
  }
  int i4 = (i - nf4) * 4;
  if (i4 >= 196608) return;
  const float* s; int o;
  if      (i4 < 16384)  { s = wq; o = i4; }
  else if (i4 < 32768)  { s = wk; o = i4 - 16384; }
  else if (i4 < 49152)  { s = wv; o = i4 - 32768; }
  else if (i4 < 65536)  { s = wo; o = i4 - 49152; }
  else if (i4 < 131072) { s = w1; o = i4 - 65536; }
  else                  { s = w2; o = i4 - 131072; }
  float4 v = *reinterpret_cast<const float4*>(s + o);
  ushort4 u; u.x = f2b(v.x); u.y = f2b(v.y); u.z = f2b(v.z); u.w = f2b(v.w);
  *reinterpret_cast<ushort4*>(wbf + i4) = u;
}

// ---------------- CSR build ----------------
__global__ void k_count(const int* __restrict__ dst, int* __restrict__ deg, int E) {
  int e = blockIdx.x * blockDim.x + threadIdx.x;
  if (e < E) atomicAdd(&deg[dst[e]], 1);
}

#define SC_EPB 1024

__global__ __launch_bounds__(256) void k_scan1(const int* __restrict__ deg,
                                               int* __restrict__ off,
                                               int* __restrict__ bsum, int n) {
  __shared__ int sh[256];
  const int t = threadIdx.x;
  int base = blockIdx.x * SC_EPB + t * 4;
  int4 v = {0, 0, 0, 0};
  if (base + 3 < n) {
    v = *reinterpret_cast<const int4*>(deg + base);
  } else {
    if (base     < n) v.x = deg[base];
    if (base + 1 < n) v.y = deg[base + 1];
    if (base + 2 < n) v.z = deg[base + 2];
    if (base + 3 < n) v.w = deg[base + 3];
  }
  int s = v.x + v.y + v.z + v.w;
  sh[t] = s;
  __syncthreads();
  #pragma unroll
  for (int d = 1; d < 256; d <<= 1) {
    int x = 0;
    if (t >= d) x = sh[t - d];
    __syncthreads();
    sh[t] += x;
    __syncthreads();
  }
  int ex = sh[t] - s;
  if (base + 3 < n) {
    int4 o; o.x = ex; o.y = ex + v.x; o.z = ex + v.x + v.y; o.w = ex + v.x + v.y + v.z;
    *reinterpret_cast<int4*>(off + base) = o;
  } else {
    if (base     < n) off[base]     = ex;
    if (base + 1 < n) off[base + 1] = ex + v.x;
    if (base + 2 < n) off[base + 2] = ex + v.x + v.y;
    if (base + 3 < n) off[base + 3] = ex + v.x + v.y + v.z;
  }
  if (t == 255) bsum[blockIdx.x] = sh[255];
}

__global__ __launch_bounds__(256) void k_scan3(int* __restrict__ off,
                                               const int* __restrict__ bsum,
                                               int nbk, int n, int E) {
  __shared__ int sadd;
  const int t = threadIdx.x;
  if (t < 64) {
    int v = (t < nbk && t < (int)blockIdx.x) ? bsum[t] : 0;
    #pragma unroll
    for (int msk = 1; msk < 64; msk <<= 1) v += __shfl_xor(v, msk);
    if (t == 0) sadd = v;
  }
  __syncthreads();
  int add = sadd;
  int base = blockIdx.x * SC_EPB + t * 4;
  if (base + 3 < n) {
    int4 v = *reinterpret_cast<int4*>(off + base);
    v.x += add; v.y += add; v.z += add; v.w += add;
    *reinterpret_cast<int4*>(off + base) = v;
  } else {
    if (base     < n) off[base]     += add;
    if (base + 1 < n) off[base + 1] += add;
    if (base + 2 < n) off[base + 2] += add;
  }
  if (blockIdx.x == 0 && t == 0) off[n] = E;
}

__global__ void k_scatter(const int* __restrict__ src, const int* __restrict__ dst,
                          const int* __restrict__ off, int* __restrict__ cur,
                          int* __restrict__ csr, int E) {
  int e = blockIdx.x * blockDim.x + threadIdx.x;
  if (e < E) {
    int d = dst[e];
    int p = off[d] + atomicAdd(&cur[d], 1);
    csr[p] = src[e];
  }
}

// =====================================================================
// k_mmT: one-tile-per-block GEMM for K=128 (round-8 proven). 512 thr,
// 8 waves (2x4 of 64x32). FLAGS: 1=bias 2=relu 4=res 8=LN(gridx==1)
// =====================================================================
template<int FLAGS, bool QKVSPLIT, bool OUTF, bool OUTB>
__global__ __launch_bounds__(512, 2) void k_mmT(
    const ushort* __restrict__ A, const ushort* __restrict__ W,
    const float* __restrict__ bias, const float* __restrict__ res,
    const float* __restrict__ lng, const float* __restrict__ lnbv,
    float* __restrict__ Cf, ushort* __restrict__ Cb, ushort* __restrict__ Cb2,
    int M, int ldc)
{
  __shared__ ushort As[128 * 128];
  __shared__ ushort Bs[128 * 128];
  __shared__ float lnred[(FLAGS & 8) ? 1024 : 4];

  const int tid = threadIdx.x;
  const int wv = tid >> 6, ln = tid & 63;
  const int bnb = blockIdx.x;
  const int mbase = blockIdx.y * 128;
  const int wrow = (wv >> 2) * 64, wcol = (wv & 3) * 32;
  const int o_base = tid * 16;

  #pragma unroll
  for (int is = 0; is < 4; ++is) {
    int o = is * 8192 + o_base;
    int row = o >> 8;
    int c = ((o >> 4) & 15) ^ (row & 15);
    int gr = min(mbase + row, M - 1);
    const ushort* sA = A + (size_t)gr * 128 + c * 8;
    __builtin_amdgcn_global_load_lds(
        (const __attribute__((address_space(1))) void*)sA,
        (__attribute__((address_space(3))) void*)((char*)As + is * 8192 + wv * 1024),
        16, 0, 0);
    const ushort* sB = W + (size_t)(bnb * 128 + row) * 128 + c * 8;
    __builtin_amdgcn_global_load_lds(
        (const __attribute__((address_space(1))) void*)sB,
        (__attribute__((address_space(3))) void*)((char*)Bs + is * 8192 + wv * 1024),
        16, 0, 0);
  }
  __syncthreads();

  f32x4 acc[4][2] = {};
  const char* AsB = (const char*)As;
  const char* BsB = (const char*)Bs;
  #pragma unroll
  for (int kk = 0; kk < 4; ++kk) {
    bf16x8 af[4], bfr[2];
    #pragma unroll
    for (int m = 0; m < 4; ++m) {
      int r = wrow + m * 16 + (ln & 15);
      int c = kk * 4 + (ln >> 4);
      af[m] = *reinterpret_cast<const bf16x8*>(AsB + r * 256 + ((c ^ (r & 15)) << 4));
    }
    #pragma unroll
    for (int n = 0; n < 2; ++n) {
      int r = wcol + n * 16 + (ln & 15);
      int c = kk * 4 + (ln >> 4);
      bfr[n] = *reinterpret_cast<const bf16x8*>(BsB + r * 256 + ((c ^ (r & 15)) << 4));
    }
    #pragma unroll
    for (int m = 0; m < 4; ++m)
      #pragma unroll
      for (int n = 0; n < 2; ++n)
        acc[m][n] = __builtin_amdgcn_mfma_f32_16x16x32_bf16(af[m], bfr[n], acc[m][n], 0, 0, 0);
  }

  if constexpr ((FLAGS & 8) != 0) {
    #pragma unroll
    for (int m = 0; m < 4; ++m)
      #pragma unroll
      for (int n = 0; n < 2; ++n) {
        int gc = wcol + n * 16 + (ln & 15);
        #pragma unroll
        for (int r = 0; r < 4; ++r) {
          int gr = mbase + wrow + m * 16 + (ln >> 4) * 4 + r;
          float v = acc[m][n][r];
          if (FLAGS & 1) v += bias[gc];
          if (FLAGS & 2) v = fmaxf(v, 0.f);
          if (FLAGS & 4) v += res[(size_t)min(gr, M - 1) * 128 + gc];
          acc[m][n][r] = v;
        }
      }
    #pragma unroll
    for (int m = 0; m < 4; ++m)
      #pragma unroll
      for (int r = 0; r < 4; ++r) {
        float sm = acc[m][0][r] + acc[m][1][r];
        float sq = acc[m][0][r] * acc[m][0][r] + acc[m][1][r] * acc[m][1][r];
        #pragma unroll
        for (int msk = 1; msk <= 8; msk <<= 1) {
          sm += __shfl_xor(sm, msk);
          sq += __shfl_xor(sq, msk);
        }
        if ((ln & 15) == 0) {
          int row = wrow + m * 16 + (ln >> 4) * 4 + r;
          lnred[row * 8 + (wv & 3) * 2]     = sm;
          lnred[row * 8 + (wv & 3) * 2 + 1] = sq;
        }
      }
    __syncthreads();
    #pragma unroll
    for (int m = 0; m < 4; ++m)
      #pragma unroll
      for (int r = 0; r < 4; ++r) {
        int row = wrow + m * 16 + (ln >> 4) * 4 + r;
        int gr = mbase + row;
        float sm = lnred[row * 8] + lnred[row * 8 + 2] + lnred[row * 8 + 4] + lnred[row * 8 + 6];
        float sq = lnred[row * 8 + 1] + lnred[row * 8 + 3] + lnred[row * 8 + 5] + lnred[row * 8 + 7];
        float mu = sm * (1.f / 128.f);
        float var = fmaxf(sq * (1.f / 128.f) - mu * mu, 0.f);
        float rstd = rsqrtf(var + LN_EPS);
        if (gr < M) {
          #pragma unroll
          for (int n = 0; n < 2; ++n) {
            int gc = wcol + n * 16 + (ln & 15);
            float y = (acc[m][n][r] - mu) * rstd * lng[gc] + lnbv[gc];
            if (OUTF) Cf[(size_t)gr * 128 + gc] = y;
            if (OUTB) Cb[(size_t)gr * 128 + gc] = f2b(y);
          }
        }
      }
  } else {
    #pragma unroll
    for (int m = 0; m < 4; ++m) {
      int gr0 = mbase + wrow + m * 16 + (ln >> 4) * 4;
      #pragma unroll
      for (int n = 0; n < 2; ++n) {
        int gcl = wcol + n * 16 + (ln & 15);
        float bsv = (FLAGS & 1) ? bias[bnb * 128 + gcl] : 0.f;
        #pragma unroll
        for (int r = 0; r < 4; ++r) {
          int gr = gr0 + r;
          if (gr >= M) continue;
          float v = acc[m][n][r] + bsv;
          if (FLAGS & 2) v = fmaxf(v, 0.f);
          if (QKVSPLIT) {
            if (bnb == 0) Cb[(size_t)gr * 128 + gcl] = f2b(v);
            else          Cb2[(size_t)gr * 256 + (bnb - 1) * 128 + gcl] = f2b(v);
          } else {
            if (OUTF) Cf[(size_t)gr * ldc + bnb * 128 + gcl] = v;
            if (OUTB) Cb[(size_t)gr * ldc + bnb * 128 + gcl] = f2b(v);
          }
        }
      }
    }
  }
}

// =====================================================================
// k_ffn: fused FFN. Per block: 64 rows. Phase1: mid = relu(h1b@W1^T+b1)
// [64x512] -> LDS (operand-swap so 4 consecutive mid-cols/lane -> 8B
// ds_write). Phase2: out = LN2(mid@W2^T + b2 + h1). W1/W2 direct global.
// 256 thr, 4 waves; wave = 128 mid-cols (ph1) / 32 out-cols (ph2).
// =====================================================================
__global__ __launch_bounds__(256, 2) void k_ffn(
    const ushort* __restrict__ h1b, const float* __restrict__ h1f,
    const ushort* __restrict__ w1, const float* __restrict__ b1,
    const ushort* __restrict__ w2, const float* __restrict__ b2,
    const float* __restrict__ lng, const float* __restrict__ lnbv,
    float* __restrict__ outp, int M)
{
  __shared__ ushort mid[64 * 512];        // 64 rows x 1024B (swizzled chunks)
  __shared__ float lnred[64 * 8];

  const int tid = threadIdx.x;
  const int wv = tid >> 6, ln = tid & 63;
  const int lr = ln & 15, hi = ln >> 4;
  const int mbase = blockIdx.x * 64;

  // ---- stage h1b tile [64][128] bf16 into mid[0:16KB] (linear dest, pre-swizzled src) ----
  #pragma unroll
  for (int is = 0; is < 4; ++is) {
    int o = is * 4096 + tid * 16;
    int row = o >> 8;                       // 256B rows
    int c = ((o >> 4) & 15) ^ (row & 15);
    int gr = min(mbase + row, M - 1);
    const ushort* s = h1b + (size_t)gr * 128 + c * 8;
    __builtin_amdgcn_global_load_lds(
        (const __attribute__((address_space(1))) void*)s,
        (__attribute__((address_space(3))) void*)((char*)mid + is * 4096 + wv * 1024),
        16, 0, 0);
  }
  __syncthreads();

  // ---- phase 1: p1[mi][hj] = mfma(W1rows, h1rows) ----
  // D layout: lane&15 -> h1 row (out row), (lane>>4)*4+r -> W1 row (mid col)
  f32x4 p1[8][4] = {};
  const char* hB = (const char*)mid;
  #pragma unroll
  for (int kk = 0; kk < 4; ++kk) {
    bf16x8 aW[8], bH[4];
    #pragma unroll
    for (int mi = 0; mi < 8; ++mi) {
      int w1row = wv * 128 + mi * 16 + lr;
      aW[mi] = *reinterpret_cast<const bf16x8*>(w1 + (size_t)w1row * 128 + kk * 32 + hi * 8);
    }
    #pragma unroll
    for (int hj = 0; hj < 4; ++hj) {
      int r = hj * 16 + lr;
      int c = kk * 4 + hi;
      bH[hj] = *reinterpret_cast<const bf16x8*>(hB + r * 256 + ((c ^ (r & 15)) << 4));
    }
    #pragma unroll
    for (int mi = 0; mi < 8; ++mi)
      #pragma unroll
      for (int hj = 0; hj < 4; ++hj)
        p1[mi][hj] = __builtin_amdgcn_mfma_f32_16x16x32_bf16(aW[mi], bH[hj], p1[mi][hj], 0, 0, 0);
  }
  __syncthreads();   // all reads of staged h1b done before overwriting

  // ---- write mid to LDS: row-major [64][512], 16-chunk XOR swizzle ----
  #pragma unroll
  for (int mi = 0; mi < 8; ++mi) {
    int mc0 = wv * 128 + mi * 16 + hi * 4;          // 4 consecutive mid cols
    float4 bv = *reinterpret_cast<const float4*>(b1 + mc0);
    int chunk = mc0 >> 3;
    int sub = (mc0 & 7) * 2;                        // 0 or 8
    #pragma unroll
    for (int hj = 0; hj < 4; ++hj) {
      int orow = hj * 16 + lr;
      ushort4 pk;
      pk.x = f2b(fmaxf(p1[mi][hj][0] + bv.x, 0.f));
      pk.y = f2b(fmaxf(p1[mi][hj][1] + bv.y, 0.f));
      pk.z = f2b(fmaxf(p1[mi][hj][2] + bv.z, 0.f));
      pk.w = f2b(fmaxf(p1[mi][hj][3] + bv.w, 0.f));
      char* dst = (char*)mid + orow * 1024 + (((chunk & 63) ^ (orow & 15)) << 4) + sub;
      *reinterpret_cast<ushort4*>(dst) = pk;
    }
  }
  __syncthreads();

  // ---- phase 2: out = LN2(mid @ W2^T + b2 + h1f) ----
  f32x4 p2[4][2] = {};
  #pragma unroll
  for (int kk = 0; kk < 16; ++kk) {
    bf16x8 aM[4], bW[2];
    int c2 = kk * 4 + hi;
    #pragma unroll
    for (int m = 0; m < 4; ++m) {
      int r = m * 16 + lr;
      aM[m] = *reinterpret_cast<const bf16x8*>((const char*)mid + r * 1024 + ((c2 ^ (r & 15)) << 4));
    }
    #pragma unroll
    for (int n = 0; n < 2; ++n) {
      int w2row = wv * 32 + n * 16 + lr;
      bW[n] = *reinterpret_cast<const bf16x8*>(w2 + (size_t)w2row * 512 + kk * 32 + hi * 8);
    }
    #pragma unroll
    for (int m = 0; m < 4; ++m)
      #pragma unroll
      for (int n = 0; n < 2; ++n)
        p2[m][n] = __builtin_amdgcn_mfma_f32_16x16x32_bf16(aM[m], bW[n], p2[m][n], 0, 0, 0);
  }

  // elementwise: +b2, +residual h1f
  #pragma unroll
  for (int m = 0; m < 4; ++m)
    #pragma unroll
    for (int n = 0; n < 2; ++n) {
      int gc = wv * 32 + n * 16 + lr;
      float bsv = b2[gc];
      #pragma unroll
      for (int r = 0; r < 4; ++r) {
        int gr = mbase + m * 16 + hi * 4 + r;
        p2[m][n][r] += bsv + h1f[(size_t)min(gr, M - 1) * 128 + gc];
      }
    }
  // row partials over this wave's 32 cols
  #pragma unroll
  for (int m = 0; m < 4; ++m)
    #pragma unroll
    for (int r = 0; r < 4; ++r) {
      float sm = p2[m][0][r] + p2[m][1][r];
      float sq = p2[m][0][r] * p2[m][0][r] + p2[m][1][r] * p2[m][1][r];
      #pragma unroll
      for (int msk = 1; msk <= 8; msk <<= 1) {
        sm += __shfl_xor(sm, msk);
        sq += __shfl_xor(sq, msk);
      }
      if (lr == 0) {
        int row = m * 16 + hi * 4 + r;
        lnred[row * 8 + wv * 2]     = sm;
        lnred[row * 8 + wv * 2 + 1] = sq;
      }
    }
  __syncthreads();
  #pragma unroll
  for (int m = 0; m < 4; ++m)
    #pragma unroll
    for (int r = 0; r < 4; ++r) {
      int row = m * 16 + hi * 4 + r;
      int gr = mbase + row;
      float sm = lnred[row * 8] + lnred[row * 8 + 2] + lnred[row * 8 + 4] + lnred[row * 8 + 6];
      float sq = lnred[row * 8 + 1] + lnred[row * 8 + 3] + lnred[row * 8 + 5] + lnred[row * 8 + 7];
      float mu = sm * (1.f / 128.f);
      float var = fmaxf(sq * (1.f / 128.f) - mu * mu, 0.f);
      float rstd = rsqrtf(var + LN_EPS);
      if (gr < M) {
        #pragma unroll
        for (int n = 0; n < 2; ++n) {
          int gc = wv * 32 + n * 16 + lr;
          outp[(size_t)gr * 128 + gc] = (p2[m][n][r] - mu) * rstd * lng[gc] + lnbv[gc];
        }
      }
    }
}

// ---------------- edge-softmax attention (round-7 proven: fixed-max) ----
__global__ __launch_bounds__(256) void k_attn(
    const ushort* __restrict__ q, const ushort* __restrict__ kv,
    const int* __restrict__ off, const int* __restrict__ csr,
    ushort* __restrict__ sav, int n)
{
  int node = blockIdx.x * 4 + (threadIdx.x >> 6);
  int lane = threadIdx.x & 63;
  if (node >= n) return;
  const int g = lane >> 3, sl = lane & 7;

  const ushort* qr = q + (size_t)node * 128 + sl * 16;
  uint4 qw0 = *reinterpret_cast<const uint4*>(qr);
  uint4 qw1 = *reinterpret_cast<const uint4*>(qr + 8);
  float qv[16];
  unpack8w(qw0, qv); unpack8w(qw1, qv + 8);

  int b = off[node], e = off[node + 1];
  float s = 0.f;
  float a[16] = {};
  int nIt = (e - b + 7) >> 3;
  int idx = b + g;
  int sn = (b < e) ? csr[min(idx, e - 1)] : 0;

  for (int i = 0; i < nIt; ++i) {
    bool act = idx < e;
    const ushort* kr = kv + (size_t)sn * 256 + sl * 16;
    uint4 kw0 = *reinterpret_cast<const uint4*>(kr);
    uint4 kw1 = *reinterpret_cast<const uint4*>(kr + 8);
    uint4 vw0 = *reinterpret_cast<const uint4*>(kr + 128);
    uint4 vw1 = *reinterpret_cast<const uint4*>(kr + 136);
    idx += 8;
    if (i + 1 < nIt) sn = csr[min(idx, e - 1)];

    float kk[16];
    unpack8w(kw0, kk); unpack8w(kw1, kk + 8);
    float p = 0.f;
    #pragma unroll
    for (int j = 0; j < 16; ++j) p = fmaf(qv[j], kk[j], p);
    float u = fminf(fmaxf(p * 0.25f, -CLAMP_V), CLAMP_V);
    float w = __expf(u - CLAMP_V);
    w = act ? w : 0.f;
    s += w;
    float vvv[16];
    unpack8w(vw0, vvv); unpack8w(vw1, vvv + 8);
    #pragma unroll
    for (int j = 0; j < 16; ++j) a[j] = fmaf(w, vvv[j], a[j]);
  }

  #pragma unroll
  for (int msk = 8; msk <= 32; msk <<= 1) {
    s += __shfl_xor(s, msk);
    #pragma unroll
    for (int j = 0; j < 16; ++j) a[j] += __shfl_xor(a[j], msk);
  }

  float inv = (s > 0.f) ? 1.f / s : 0.f;
  if (g == 0) {
    uint w[8];
    #pragma unroll
    for (int j = 0; j < 8; ++j)
      w[j] = (uint)f2b(a[2 * j] * inv) | ((uint)f2b(a[2 * j + 1] * inv) << 16);
    ushort* outp = sav + (size_t)node * 128 + sl * 16;
    uint4 o0 = {w[0], w[1], w[2], w[3]};
    uint4 o1 = {w[4], w[5], w[6], w[7]};
    *reinterpret_cast<uint4*>(outp) = o0;
    *reinterpret_cast<uint4*>(outp + 8) = o1;
  }
}

extern "C" void kernel_launch(void* const* d_in, const int* in_sizes, int n_in,
                              void* d_out, int out_size, void* d_ws, size_t ws_size,
                              hipStream_t stream)
{
  const float* feat = (const float*)d_in[0];
  const int*   src  = (const int*)d_in[1];
  const int*   dst  = (const int*)d_in[2];
  const float* Wq   = (const float*)d_in[3];
  const float* Wk   = (const float*)d_in[4];
  const float* Wv   = (const float*)d_in[5];
  const float* Wo   = (const float*)d_in[6];
  const float* ln1g = (const float*)d_in[7];
  const float* ln1b = (const float*)d_in[8];
  const float* W1   = (const float*)d_in[9];
  const float* b1   = (const float*)d_in[10];
  const float* W2   = (const float*)d_in[11];
  const float* b2   = (const float*)d_in[12];
  const float* ln2g = (const float*)d_in[13];
  const float* ln2b = (const float*)d_in[14];
  float* out = (float*)d_out;

  const int N = in_sizes[0] / DM;
  const int E = in_sizes[1];
  const size_t NB = (size_t)N;

  char* wsb = (char*)d_ws;
  ushort* q_bf    = (ushort*)wsb;
  ushort* kv_bf   = (ushort*)(wsb + NB * 256);
  ushort* sav_bf  = (ushort*)(wsb + NB * 768);
  float*  h1      = (float*)(wsb + NB * 1024);
  ushort* h1b     = (ushort*)(wsb + NB * 1536);
  ushort* feat_bf = (ushort*)(wsb + NB * 1792);
  ushort* wbf     = (ushort*)(wsb + NB * 2048);
  ushort* wqkv_bf = wbf;
  ushort* wo_bf   = wbf + 49152;
  ushort* w1_bf   = wbf + 65536;
  ushort* w2_bf   = wbf + 131072;
  int* ib  = (int*)(wbf + 196608);
  int* deg = ib;
  int* cur = ib + N;
  int* off = ib + 2 * N;
  int* csr = ib + 3 * N + 1;
  int* bsum = csr + E;

  hipMemsetAsync(deg, 0, 2 * (size_t)N * sizeof(int), stream);

  int nf4 = N * DM / 4;
  k_castall<<<(nf4 + 49152 + 255) / 256, 256, 0, stream>>>(
      feat, Wq, Wk, Wv, Wo, W1, W2, feat_bf, wbf, nf4);

  int eb = (E + 255) / 256;
  int nbk = (N + SC_EPB - 1) / SC_EPB;
  k_count<<<eb, 256, 0, stream>>>(dst, deg, E);
  k_scan1<<<nbk, 256, 0, stream>>>(deg, off, bsum, N);
  k_scan3<<<nbk, 256, 0, stream>>>(off, bsum, nbk, N, E);
  k_scatter<<<eb, 256, 0, stream>>>(src, dst, off, cur, csr, E);

  int nb4 = (N + 3) / 4;
  const int nT = (N + 127) / 128;   // 313

  // qkv: grid (3, nT), split output q_bf | kv_bf
  k_mmT<0, true, false, true><<<dim3(3, nT), 512, 0, stream>>>(
      feat_bf, wqkv_bf, nullptr, nullptr, nullptr, nullptr,
      nullptr, q_bf, kv_bf, N, 128);

  k_attn<<<nb4, 256, 0, stream>>>(q_bf, kv_bf, off, csr, sav_bf, N);

  // h1 = LN1(sav @ Wo^T + feat) -> h1 f32 + h1b bf16
  k_mmT<4 | 8, false, true, true><<<dim3(1, nT), 512, 0, stream>>>(
      sav_bf, wo_bf, nullptr, feat, ln1g, ln1b, h1, h1b, nullptr, N, 128);

  // fused FFN: out = LN2(relu(h1b@W1^T+b1)@W2^T + b2 + h1)
  const int nF = (N + 63) / 64;     // 625
  k_ffn<<<nF, 256, 0, stream>>>(
      h1b, h1, w1_bf, b1, w2_bf, b2, ln2g, ln2b, out, N);
}

// Round 11
// 194.327 us; speedup vs baseline: 1.2215x; 1.0074x over previous
//
#include <hip/hip_runtime.h>

#define DM 128
#define DFF 512
#define CLAMP_V 5.0f
#define LN_EPS 1e-5f

typedef __attribute__((ext_vector_type(8))) short bf16x8;
typedef __attribute__((ext_vector_type(4))) float f32x4;

__device__ __forceinline__ float b2f(ushort u) {
  union { uint u; float f; } x; x.u = ((uint)u) << 16; return x.f;
}
__device__ __forceinline__ ushort f2b(float f) {
  union { float f; uint u; } x; x.f = f;
  uint r = x.u + 0x7FFFu + ((x.u >> 16) & 1u);
  return (ushort)(r >> 16);
}
__device__ __forceinline__ void unpackw(uint w, float& lo, float& hi) {
  union { uint u; float f; } A, B;
  A.u = w << 16; B.u = w & 0xFFFF0000u;
  lo = A.f; hi = B.f;
}
__device__ __forceinline__ void unpack8w(uint4 w, float* o) {
  unpackw(w.x, o[0], o[1]); unpackw(w.y, o[2], o[3]);
  unpackw(w.z, o[4], o[5]); unpackw(w.w, o[6], o[7]);
}

// ---------------- fused prep: feat cast + weight cast + degree count ----------------
__global__ void k_prep(const float* __restrict__ feat,
                       const float* __restrict__ wq, const float* __restrict__ wk,
                       const float* __restrict__ wv, const float* __restrict__ wo,
                       const float* __restrict__ w1, const float* __restrict__ w2,
                       ushort* __restrict__ feat_bf, ushort* __restrict__ wbf,
                       const int* __restrict__ dst, int* __restrict__ deg,
                       int nf4, int castBlocks, int E) {
  if ((int)blockIdx.x >= castBlocks) {
    int e = ((int)blockIdx.x - castBlocks) * 256 + threadIdx.x;
    if (e < E) atomicAdd(&deg[dst[e]], 1);
    return;
  }
  int i = blockIdx.x * 256 + threadIdx.x;
  if (i < nf4) {
    float4 v = *reinterpret_cast<const float4*>(feat + i * 4);
    ushort4 o; o.x = f2b(v.x); o.y = f2b(v.y); o.z = f2b(v.z); o.w = f2b(v.w);
    *reinterpret_cast<ushort4*>(feat_bf + i * 4) = o;
    return;
  }
  int i4 = (i - nf4) * 4;
  if (i4 >= 196608) return;
  const float* s; int o;
  if      (i4 < 16384)  { s = wq; o = i4; }
  else if (i4 < 32768)  { s = wk; o = i4 - 16384; }
  else if (i4 < 49152)  { s = wv; o = i4 - 32768; }
  else if (i4 < 65536)  { s = wo; o = i4 - 49152; }
  else if (i4 < 131072) { s = w1; o = i4 - 65536; }
  else                  { s = w2; o = i4 - 131072; }
  float4 v = *reinterpret_cast<const float4*>(s + o);
  ushort4 u; u.x = f2b(v.x); u.y = f2b(v.y); u.z = f2b(v.z); u.w = f2b(v.w);
  *reinterpret_cast<ushort4*>(wbf + i4) = u;
}

#define SC_EPB 1024

__global__ __launch_bounds__(256) void k_scan1(const int* __restrict__ deg,
                                               int* __restrict__ off,
                                               int* __restrict__ bsum, int n) {
  __shared__ int sh[256];
  const int t = threadIdx.x;
  int base = blockIdx.x * SC_EPB + t * 4;
  int4 v = {0, 0, 0, 0};
  if (base + 3 < n) {
    v = *reinterpret_cast<const int4*>(deg + base);
  } else {
    if (base     < n) v.x = deg[base];
    if (base + 1 < n) v.y = deg[base + 1];
    if (base + 2 < n) v.z = deg[base + 2];
    if (base + 3 < n) v.w = deg[base + 3];
  }
  int s = v.x + v.y + v.z + v.w;
  sh[t] = s;
  __syncthreads();
  #pragma unroll
  for (int d = 1; d < 256; d <<= 1) {
    int x = 0;
    if (t >= d) x = sh[t - d];
    __syncthreads();
    sh[t] += x;
    __syncthreads();
  }
  int ex = sh[t] - s;
  if (base + 3 < n) {
    int4 o; o.x = ex; o.y = ex + v.x; o.z = ex + v.x + v.y; o.w = ex + v.x + v.y + v.z;
    *reinterpret_cast<int4*>(off + base) = o;
  } else {
    if (base     < n) off[base]     = ex;
    if (base + 1 < n) off[base + 1] = ex + v.x;
    if (base + 2 < n) off[base + 2] = ex + v.x + v.y;
    if (base + 3 < n) off[base + 3] = ex + v.x + v.y + v.z;
  }
  if (t == 255) bsum[blockIdx.x] = sh[255];
}

__global__ __launch_bounds__(256) void k_scan3(int* __restrict__ off,
                                               const int* __restrict__ bsum,
                                               int nbk, int n, int E) {
  __shared__ int sadd;
  const int t = threadIdx.x;
  if (t < 64) {
    int v = (t < nbk && t < (int)blockIdx.x) ? bsum[t] : 0;
    #pragma unroll
    for (int msk = 1; msk < 64; msk <<= 1) v += __shfl_xor(v, msk);
    if (t == 0) sadd = v;
  }
  __syncthreads();
  int add = sadd;
  int base = blockIdx.x * SC_EPB + t * 4;
  if (base + 3 < n) {
    int4 v = *reinterpret_cast<int4*>(off + base);
    v.x += add; v.y += add; v.z += add; v.w += add;
    *reinterpret_cast<int4*>(off + base) = v;
  } else {
    if (base     < n) off[base]     += add;
    if (base + 1 < n) off[base + 1] += add;
    if (base + 2 < n) off[base + 2] += add;
  }
  if (blockIdx.x == 0 && t == 0) off[n] = E;
}

__global__ void k_scatter(const int* __restrict__ src, const int* __restrict__ dst,
                          const int* __restrict__ off, int* __restrict__ cur,
                          int* __restrict__ csr, int E) {
  int e = blockIdx.x * blockDim.x + threadIdx.x;
  if (e < E) {
    int d = dst[e];
    int p = off[d] + atomicAdd(&cur[d], 1);
    csr[p] = src[e];
  }
}

// =====================================================================
// k_mmT: one-tile-per-block GEMM for K=128 (round-8 proven). 512 thr,
// 8 waves (2x4 of 64x32). FLAGS: 1=bias 2=relu 4=res 8=LN(gridx==1)
// =====================================================================
template<int FLAGS, bool QKVSPLIT, bool OUTF, bool OUTB>
__global__ __launch_bounds__(512, 2) void k_mmT(
    const ushort* __restrict__ A, const ushort* __restrict__ W,
    const float* __restrict__ bias, const float* __restrict__ res,
    const float* __restrict__ lng, const float* __restrict__ lnbv,
    float* __restrict__ Cf, ushort* __restrict__ Cb, ushort* __restrict__ Cb2,
    int M, int ldc)
{
  __shared__ ushort As[128 * 128];
  __shared__ ushort Bs[128 * 128];
  __shared__ float lnred[(FLAGS & 8) ? 1024 : 4];

  const int tid = threadIdx.x;
  const int wv = tid >> 6, ln = tid & 63;
  const int bnb = blockIdx.x;
  const int mbase = blockIdx.y * 128;
  const int wrow = (wv >> 2) * 64, wcol = (wv & 3) * 32;
  const int o_base = tid * 16;

  #pragma unroll
  for (int is = 0; is < 4; ++is) {
    int o = is * 8192 + o_base;
    int row = o >> 8;
    int c = ((o >> 4) & 15) ^ (row & 15);
    int gr = min(mbase + row, M - 1);
    const ushort* sA = A + (size_t)gr * 128 + c * 8;
    __builtin_amdgcn_global_load_lds(
        (const __attribute__((address_space(1))) void*)sA,
        (__attribute__((address_space(3))) void*)((char*)As + is * 8192 + wv * 1024),
        16, 0, 0);
    const ushort* sB = W + (size_t)(bnb * 128 + row) * 128 + c * 8;
    __builtin_amdgcn_global_load_lds(
        (const __attribute__((address_space(1))) void*)sB,
        (__attribute__((address_space(3))) void*)((char*)Bs + is * 8192 + wv * 1024),
        16, 0, 0);
  }
  __syncthreads();

  f32x4 acc[4][2] = {};
  const char* AsB = (const char*)As;
  const char* BsB = (const char*)Bs;
  #pragma unroll
  for (int kk = 0; kk < 4; ++kk) {
    bf16x8 af[4], bfr[2];
    #pragma unroll
    for (int m = 0; m < 4; ++m) {
      int r = wrow + m * 16 + (ln & 15);
      int c = kk * 4 + (ln >> 4);
      af[m] = *reinterpret_cast<const bf16x8*>(AsB + r * 256 + ((c ^ (r & 15)) << 4));
    }
    #pragma unroll
    for (int n = 0; n < 2; ++n) {
      int r = wcol + n * 16 + (ln & 15);
      int c = kk * 4 + (ln >> 4);
      bfr[n] = *reinterpret_cast<const bf16x8*>(BsB + r * 256 + ((c ^ (r & 15)) << 4));
    }
    #pragma unroll
    for (int m = 0; m < 4; ++m)
      #pragma unroll
      for (int n = 0; n < 2; ++n)
        acc[m][n] = __builtin_amdgcn_mfma_f32_16x16x32_bf16(af[m], bfr[n], acc[m][n], 0, 0, 0);
  }

  if constexpr ((FLAGS & 8) != 0) {
    #pragma unroll
    for (int m = 0; m < 4; ++m)
      #pragma unroll
      for (int n = 0; n < 2; ++n) {
        int gc = wcol + n * 16 + (ln & 15);
        #pragma unroll
        for (int r = 0; r < 4; ++r) {
          int gr = mbase + wrow + m * 16 + (ln >> 4) * 4 + r;
          float v = acc[m][n][r];
          if (FLAGS & 1) v += bias[gc];
          if (FLAGS & 2) v = fmaxf(v, 0.f);
          if (FLAGS & 4) v += res[(size_t)min(gr, M - 1) * 128 + gc];
          acc[m][n][r] = v;
        }
      }
    #pragma unroll
    for (int m = 0; m < 4; ++m)
      #pragma unroll
      for (int r = 0; r < 4; ++r) {
        float sm = acc[m][0][r] + acc[m][1][r];
        float sq = acc[m][0][r] * acc[m][0][r] + acc[m][1][r] * acc[m][1][r];
        #pragma unroll
        for (int msk = 1; msk <= 8; msk <<= 1) {
          sm += __shfl_xor(sm, msk);
          sq += __shfl_xor(sq, msk);
        }
        if ((ln & 15) == 0) {
          int row = wrow + m * 16 + (ln >> 4) * 4 + r;
          lnred[row * 8 + (wv & 3) * 2]     = sm;
          lnred[row * 8 + (wv & 3) * 2 + 1] = sq;
        }
      }
    __syncthreads();
    #pragma unroll
    for (int m = 0; m < 4; ++m)
      #pragma unroll
      for (int r = 0; r < 4; ++r) {
        int row = wrow + m * 16 + (ln >> 4) * 4 + r;
        int gr = mbase + row;
        float sm = lnred[row * 8] + lnred[row * 8 + 2] + lnred[row * 8 + 4] + lnred[row * 8 + 6];
        float sq = lnred[row * 8 + 1] + lnred[row * 8 + 3] + lnred[row * 8 + 5] + lnred[row * 8 + 7];
        float mu = sm * (1.f / 128.f);
        float var = fmaxf(sq * (1.f / 128.f) - mu * mu, 0.f);
        float rstd = rsqrtf(var + LN_EPS);
        if (gr < M) {
          #pragma unroll
          for (int n = 0; n < 2; ++n) {
            int gc = wcol + n * 16 + (ln & 15);
            float y = (acc[m][n][r] - mu) * rstd * lng[gc] + lnbv[gc];
            if (OUTF) Cf[(size_t)gr * 128 + gc] = y;
            if (OUTB) Cb[(size_t)gr * 128 + gc] = f2b(y);
          }
        }
      }
  } else {
    #pragma unroll
    for (int m = 0; m < 4; ++m) {
      int gr0 = mbase + wrow + m * 16 + (ln >> 4) * 4;
      #pragma unroll
      for (int n = 0; n < 2; ++n) {
        int gcl = wcol + n * 16 + (ln & 15);
        float bsv = (FLAGS & 1) ? bias[bnb * 128 + gcl] : 0.f;
        #pragma unroll
        for (int r = 0; r < 4; ++r) {
          int gr = gr0 + r;
          if (gr >= M) continue;
          float v = acc[m][n][r] + bsv;
          if (FLAGS & 2) v = fmaxf(v, 0.f);
          if (QKVSPLIT) {
            if (bnb == 0) Cb[(size_t)gr * 128 + gcl] = f2b(v);
            else          Cb2[(size_t)gr * 256 + (bnb - 1) * 128 + gcl] = f2b(v);
          } else {
            if (OUTF) Cf[(size_t)gr * ldc + bnb * 128 + gcl] = v;
            if (OUTB) Cb[(size_t)gr * ldc + bnb * 128 + gcl] = f2b(v);
          }
        }
      }
    }
  }
}

// =====================================================================
// k_ffn: fused FFN, 512 thr / 8 waves (2x the latency hiding of r10).
// Per block: 64 rows. Phase1: wave owns 64 mid-cols; Phase2: wave owns
// 16 out-cols. mid [64][512] bf16 in LDS (16-chunk XOR swizzle).
// =====================================================================
__global__ __launch_bounds__(512, 4) void k_ffn(
    const ushort* __restrict__ h1b, const float* __restrict__ h1f,
    const ushort* __restrict__ w1, const float* __restrict__ b1,
    const ushort* __restrict__ w2, const float* __restrict__ b2,
    const float* __restrict__ lng, const float* __restrict__ lnbv,
    float* __restrict__ outp, int M)
{
  __shared__ ushort mid[64 * 512];        // 64 rows x 1024B
  __shared__ float lnred[64 * 16];

  const int tid = threadIdx.x;
  const int wv = tid >> 6, ln = tid & 63;
  const int lr = ln & 15, hi = ln >> 4;
  const int mbase = blockIdx.x * 64;

  // ---- stage h1b tile [64][128] bf16 into mid[0:16KB] ----
  #pragma unroll
  for (int is = 0; is < 2; ++is) {
    int o = is * 8192 + tid * 16;
    int row = o >> 8;                       // 256B rows
    int c = ((o >> 4) & 15) ^ (row & 15);
    int gr = min(mbase + row, M - 1);
    const ushort* s = h1b + (size_t)gr * 128 + c * 8;
    __builtin_amdgcn_global_load_lds(
        (const __attribute__((address_space(1))) void*)s,
        (__attribute__((address_space(3))) void*)((char*)mid + is * 8192 + wv * 1024),
        16, 0, 0);
  }
  __syncthreads();

  // ---- phase 1: mid = relu(h1b @ W1^T + b1); wave owns mid cols [wv*64, +64) ----
  f32x4 p1[4][4] = {};
  const char* hB = (const char*)mid;
  #pragma unroll
  for (int kk = 0; kk < 4; ++kk) {
    bf16x8 aW[4], bH[4];
    #pragma unroll
    for (int mi = 0; mi < 4; ++mi) {
      int w1row = wv * 64 + mi * 16 + lr;
      aW[mi] = *reinterpret_cast<const bf16x8*>(w1 + (size_t)w1row * 128 + kk * 32 + hi * 8);
    }
    #pragma unroll
    for (int hj = 0; hj < 4; ++hj) {
      int r = hj * 16 + lr;
      int c = kk * 4 + hi;
      bH[hj] = *reinterpret_cast<const bf16x8*>(hB + r * 256 + ((c ^ (r & 15)) << 4));
    }
    #pragma unroll
    for (int mi = 0; mi < 4; ++mi)
      #pragma unroll
      for (int hj = 0; hj < 4; ++hj)
        p1[mi][hj] = __builtin_amdgcn_mfma_f32_16x16x32_bf16(aW[mi], bH[hj], p1[mi][hj], 0, 0, 0);
  }
  __syncthreads();   // staged h1b fully consumed before overwrite

  // ---- write mid: row-major [64][512] bf16, 16B-chunk XOR swizzle ----
  #pragma unroll
  for (int mi = 0; mi < 4; ++mi) {
    int mc0 = wv * 64 + mi * 16 + hi * 4;           // 4 consecutive mid cols
    float4 bv = *reinterpret_cast<const float4*>(b1 + mc0);
    int chunk = mc0 >> 3;
    int sub = (mc0 & 7) * 2;                        // 0 or 8
    #pragma unroll
    for (int hj = 0; hj < 4; ++hj) {
      int orow = hj * 16 + lr;
      ushort4 pk;
      pk.x = f2b(fmaxf(p1[mi][hj][0] + bv.x, 0.f));
      pk.y = f2b(fmaxf(p1[mi][hj][1] + bv.y, 0.f));
      pk.z = f2b(fmaxf(p1[mi][hj][2] + bv.z, 0.f));
      pk.w = f2b(fmaxf(p1[mi][hj][3] + bv.w, 0.f));
      char* dstp = (char*)mid + orow * 1024 + (((chunk & 63) ^ (orow & 15)) << 4) + sub;
      *reinterpret_cast<ushort4*>(dstp) = pk;
    }
  }
  __syncthreads();

  // ---- phase 2: out = LN2(mid @ W2^T + b2 + h1f); wave owns out cols [wv*16, +16) ----
  f32x4 p2[4] = {};
  #pragma unroll
  for (int kk = 0; kk < 16; ++kk) {
    bf16x8 aM[4], bW;
    int c2 = kk * 4 + hi;
    #pragma unroll
    for (int m = 0; m < 4; ++m) {
      int r = m * 16 + lr;
      aM[m] = *reinterpret_cast<const bf16x8*>((const char*)mid + r * 1024 + ((c2 ^ (r & 15)) << 4));
    }
    int w2row = wv * 16 + lr;
    bW = *reinterpret_cast<const bf16x8*>(w2 + (size_t)w2row * 512 + kk * 32 + hi * 8);
    #pragma unroll
    for (int m = 0; m < 4; ++m)
      p2[m] = __builtin_amdgcn_mfma_f32_16x16x32_bf16(aM[m], bW, p2[m], 0, 0, 0);
  }

  // elementwise: +b2, +residual h1f
  {
    int gc = wv * 16 + lr;
    float bsv = b2[gc];
    #pragma unroll
    for (int m = 0; m < 4; ++m)
      #pragma unroll
      for (int r = 0; r < 4; ++r) {
        int gr = mbase + m * 16 + hi * 4 + r;
        p2[m][r] += bsv + h1f[(size_t)min(gr, M - 1) * 128 + gc];
      }
  }
  // row partials over this wave's 16 cols
  #pragma unroll
  for (int m = 0; m < 4; ++m)
    #pragma unroll
    for (int r = 0; r < 4; ++r) {
      float sm = p2[m][r];
      float sq = p2[m][r] * p2[m][r];
      #pragma unroll
      for (int msk = 1; msk <= 8; msk <<= 1) {
        sm += __shfl_xor(sm, msk);
        sq += __shfl_xor(sq, msk);
      }
      if (lr == 0) {
        int row = m * 16 + hi * 4 + r;
        lnred[row * 16 + wv * 2]     = sm;
        lnred[row * 16 + wv * 2 + 1] = sq;
      }
    }
  __syncthreads();
  #pragma unroll
  for (int m = 0; m < 4; ++m)
    #pragma unroll
    for (int r = 0; r < 4; ++r) {
      int row = m * 16 + hi * 4 + r;
      int gr = mbase + row;
      float sm = 0.f, sq = 0.f;
      #pragma unroll
      for (int w = 0; w < 8; ++w) {
        sm += lnred[row * 16 + w * 2];
        sq += lnred[row * 16 + w * 2 + 1];
      }
      float mu = sm * (1.f / 128.f);
      float var = fmaxf(sq * (1.f / 128.f) - mu * mu, 0.f);
      float rstd = rsqrtf(var + LN_EPS);
      if (gr < M) {
        int gc = wv * 16 + lr;
        outp[(size_t)gr * 128 + gc] = (p2[m][r] - mu) * rstd * lng[gc] + lnbv[gc];
      }
    }
}

// ---------------- edge-softmax attention (round-7 proven: fixed-max) ----
__global__ __launch_bounds__(256) void k_attn(
    const ushort* __restrict__ q, const ushort* __restrict__ kv,
    const int* __restrict__ off, const int* __restrict__ csr,
    ushort* __restrict__ sav, int n)
{
  int node = blockIdx.x * 4 + (threadIdx.x >> 6);
  int lane = threadIdx.x & 63;
  if (node >= n) return;
  const int g = lane >> 3, sl = lane & 7;

  const ushort* qr = q + (size_t)node * 128 + sl * 16;
  uint4 qw0 = *reinterpret_cast<const uint4*>(qr);
  uint4 qw1 = *reinterpret_cast<const uint4*>(qr + 8);
  float qv[16];
  unpack8w(qw0, qv); unpack8w(qw1, qv + 8);

  int b = off[node], e = off[node + 1];
  float s = 0.f;
  float a[16] = {};
  int nIt = (e - b + 7) >> 3;
  int idx = b + g;
  int sn = (b < e) ? csr[min(idx, e - 1)] : 0;

  for (int i = 0; i < nIt; ++i) {
    bool act = idx < e;
    const ushort* kr = kv + (size_t)sn * 256 + sl * 16;
    uint4 kw0 = *reinterpret_cast<const uint4*>(kr);
    uint4 kw1 = *reinterpret_cast<const uint4*>(kr + 8);
    uint4 vw0 = *reinterpret_cast<const uint4*>(kr + 128);
    uint4 vw1 = *reinterpret_cast<const uint4*>(kr + 136);
    idx += 8;
    if (i + 1 < nIt) sn = csr[min(idx, e - 1)];

    float kk[16];
    unpack8w(kw0, kk); unpack8w(kw1, kk + 8);
    float p = 0.f;
    #pragma unroll
    for (int j = 0; j < 16; ++j) p = fmaf(qv[j], kk[j], p);
    float u = fminf(fmaxf(p * 0.25f, -CLAMP_V), CLAMP_V);
    float w = __expf(u - CLAMP_V);
    w = act ? w : 0.f;
    s += w;
    float vvv[16];
    unpack8w(vw0, vvv); unpack8w(vw1, vvv + 8);
    #pragma unroll
    for (int j = 0; j < 16; ++j) a[j] = fmaf(w, vvv[j], a[j]);
  }

  #pragma unroll
  for (int msk = 8; msk <= 32; msk <<= 1) {
    s += __shfl_xor(s, msk);
    #pragma unroll
    for (int j = 0; j < 16; ++j) a[j] += __shfl_xor(a[j], msk);
  }

  float inv = (s > 0.f) ? 1.f / s : 0.f;
  if (g == 0) {
    uint w[8];
    #pragma unroll
    for (int j = 0; j < 8; ++j)
      w[j] = (uint)f2b(a[2 * j] * inv) | ((uint)f2b(a[2 * j + 1] * inv) << 16);
    ushort* outp = sav + (size_t)node * 128 + sl * 16;
    uint4 o0 = {w[0], w[1], w[2], w[3]};
    uint4 o1 = {w[4], w[5], w[6], w[7]};
    *reinterpret_cast<uint4*>(outp) = o0;
    *reinterpret_cast<uint4*>(outp + 8) = o1;
  }
}

extern "C" void kernel_launch(void* const* d_in, const int* in_sizes, int n_in,
                              void* d_out, int out_size, void* d_ws, size_t ws_size,
                              hipStream_t stream)
{
  const float* feat = (const float*)d_in[0];
  const int*   src  = (const int*)d_in[1];
  const int*   dst  = (const int*)d_in[2];
  const float* Wq   = (const float*)d_in[3];
  const float* Wk   = (const float*)d_in[4];
  const float* Wv   = (const float*)d_in[5];
  const float* Wo   = (const float*)d_in[6];
  const float* ln1g = (const float*)d_in[7];
  const float* ln1b = (const float*)d_in[8];
  const float* W1   = (const float*)d_in[9];
  const float* b1   = (const float*)d_in[10];
  const float* W2   = (const float*)d_in[11];
  const float* b2   = (const float*)d_in[12];
  const float* ln2g = (const float*)d_in[13];
  const float* ln2b = (const float*)d_in[14];
  float* out = (float*)d_out;

  const int N = in_sizes[0] / DM;
  const int E = in_sizes[1];
  const size_t NB = (size_t)N;

  char* wsb = (char*)d_ws;
  ushort* q_bf    = (ushort*)wsb;
  ushort* kv_bf   = (ushort*)(wsb + NB * 256);
  ushort* sav_bf  = (ushort*)(wsb + NB * 768);
  float*  h1      = (float*)(wsb + NB * 1024);
  ushort* h1b     = (ushort*)(wsb + NB * 1536);
  ushort* feat_bf = (ushort*)(wsb + NB * 1792);
  ushort* wbf     = (ushort*)(wsb + NB * 2048);
  ushort* wqkv_bf = wbf;
  ushort* wo_bf   = wbf + 49152;
  ushort* w1_bf   = wbf + 65536;
  ushort* w2_bf   = wbf + 131072;
  int* ib  = (int*)(wbf + 196608);
  int* deg = ib;
  int* cur = ib + N;
  int* off = ib + 2 * N;
  int* csr = ib + 3 * N + 1;
  int* bsum = csr + E;

  hipMemsetAsync(deg, 0, 2 * (size_t)N * sizeof(int), stream);

  int nf4 = N * DM / 4;
  int castBlocks = (nf4 + 49152 + 255) / 256;
  int cntBlocks = (E + 255) / 256;
  k_prep<<<castBlocks + cntBlocks, 256, 0, stream>>>(
      feat, Wq, Wk, Wv, Wo, W1, W2, feat_bf, wbf, dst, deg, nf4, castBlocks, E);

  int nbk = (N + SC_EPB - 1) / SC_EPB;
  k_scan1<<<nbk, 256, 0, stream>>>(deg, off, bsum, N);
  k_scan3<<<nbk, 256, 0, stream>>>(off, bsum, nbk, N, E);
  k_scatter<<<cntBlocks, 256, 0, stream>>>(src, dst, off, cur, csr, E);

  int nb4 = (N + 3) / 4;
  const int nT = (N + 127) / 128;   // 313

  // qkv: grid (3, nT), split output q_bf | kv_bf
  k_mmT<0, true, false, true><<<dim3(3, nT), 512, 0, stream>>>(
      feat_bf, wqkv_bf, nullptr, nullptr, nullptr, nullptr,
      nullptr, q_bf, kv_bf, N, 128);

  k_attn<<<nb4, 256, 0, stream>>>(q_bf, kv_bf, off, csr, sav_bf, N);

  // h1 = LN1(sav @ Wo^T + feat) -> h1 f32 + h1b bf16
  k_mmT<4 | 8, false, true, true><<<dim3(1, nT), 512, 0, stream>>>(
      sav_bf, wo_bf, nullptr, feat, ln1g, ln1b, h1, h1b, nullptr, N, 128);

  // fused FFN: out = LN2(relu(h1b@W1^T+b1)@W2^T + b2 + h1)
  const int nF = (N + 63) / 64;     // 625
  k_ffn<<<nF, 512, 0, stream>>>(
      h1b, h1, w1_bf, b1, w2_bf, b2, ln2g, ln2b, out, N);
}

// Round 12
// 193.241 us; speedup vs baseline: 1.2284x; 1.0056x over previous
//
#include <hip/hip_runtime.h>

#define DM 128
#define DFF 512
#define CLAMP_V 5.0f
#define LN_EPS 1e-5f

typedef __attribute__((ext_vector_type(8))) short bf16x8;
typedef __attribute__((ext_vector_type(4))) float f32x4;

__device__ __forceinline__ float b2f(ushort u) {
  union { uint u; float f; } x; x.u = ((uint)u) << 16; return x.f;
}
__device__ __forceinline__ ushort f2b(float f) {
  union { float f; uint u; } x; x.f = f;
  uint r = x.u + 0x7FFFu + ((x.u >> 16) & 1u);
  return (ushort)(r >> 16);
}
__device__ __forceinline__ void unpackw(uint w, float& lo, float& hi) {
  union { uint u; float f; } A, B;
  A.u = w << 16; B.u = w & 0xFFFF0000u;
  lo = A.f; hi = B.f;
}
__device__ __forceinline__ void unpack8w(uint4 w, float* o) {
  unpackw(w.x, o[0], o[1]); unpackw(w.y, o[2], o[3]);
  unpackw(w.z, o[4], o[5]); unpackw(w.w, o[6], o[7]);
}

// ---------------- fused prep: feat cast + weight cast + degree count ----------------
__global__ void k_prep(const float* __restrict__ feat,
                       const float* __restrict__ wq, const float* __restrict__ wk,
                       const float* __restrict__ wv, const float* __restrict__ wo,
                       const float* __restrict__ w1, const float* __restrict__ w2,
                       ushort* __restrict__ feat_bf, ushort* __restrict__ wbf,
                       const int* __restrict__ dst, int* __restrict__ deg,
                       int nf4, int castBlocks, int E) {
  if ((int)blockIdx.x >= castBlocks) {
    int e = ((int)blockIdx.x - castBlocks) * 256 + threadIdx.x;
    if (e < E) atomicAdd(&deg[dst[e]], 1);
    return;
  }
  int i = blockIdx.x * 256 + threadIdx.x;
  if (i < nf4) {
    float4 v = *reinterpret_cast<const float4*>(feat + i * 4);
    ushort4 o; o.x = f2b(v.x); o.y = f2b(v.y); o.z = f2b(v.z); o.w = f2b(v.w);
    *reinterpret_cast<ushort4*>(feat_bf + i * 4) = o;
    return;
  }
  int i4 = (i - nf4) * 4;
  if (i4 >= 196608) return;
  const float* s; int o;
  if      (i4 < 16384)  { s = wq; o = i4; }
  else if (i4 < 32768)  { s = wk; o = i4 - 16384; }
  else if (i4 < 49152)  { s = wv; o = i4 - 32768; }
  else if (i4 < 65536)  { s = wo; o = i4 - 49152; }
  else if (i4 < 131072) { s = w1; o = i4 - 65536; }
  else                  { s = w2; o = i4 - 131072; }
  float4 v = *reinterpret_cast<const float4*>(s + o);
  ushort4 u; u.x = f2b(v.x); u.y = f2b(v.y); u.z = f2b(v.z); u.w = f2b(v.w);
  *reinterpret_cast<ushort4*>(wbf + i4) = u;
}

#define SC_EPB 1024

__global__ __launch_bounds__(256) void k_scan1(const int* __restrict__ deg,
                                               int* __restrict__ off,
                                               int* __restrict__ bsum, int n) {
  __shared__ int sh[256];
  const int t = threadIdx.x;
  int base = blockIdx.x * SC_EPB + t * 4;
  int4 v = {0, 0, 0, 0};
  if (base + 3 < n) {
    v = *reinterpret_cast<const int4*>(deg + base);
  } else {
    if (base     < n) v.x = deg[base];
    if (base + 1 < n) v.y = deg[base + 1];
    if (base + 2 < n) v.z = deg[base + 2];
    if (base + 3 < n) v.w = deg[base + 3];
  }
  int s = v.x + v.y + v.z + v.w;
  sh[t] = s;
  __syncthreads();
  #pragma unroll
  for (int d = 1; d < 256; d <<= 1) {
    int x = 0;
    if (t >= d) x = sh[t - d];
    __syncthreads();
    sh[t] += x;
    __syncthreads();
  }
  int ex = sh[t] - s;
  if (base + 3 < n) {
    int4 o; o.x = ex; o.y = ex + v.x; o.z = ex + v.x + v.y; o.w = ex + v.x + v.y + v.z;
    *reinterpret_cast<int4*>(off + base) = o;
  } else {
    if (base     < n) off[base]     = ex;
    if (base + 1 < n) off[base + 1] = ex + v.x;
    if (base + 2 < n) off[base + 2] = ex + v.x + v.y;
    if (base + 3 < n) off[base + 3] = ex + v.x + v.y + v.z;
  }
  if (t == 255) bsum[blockIdx.x] = sh[255];
}

__global__ __launch_bounds__(256) void k_scan3(int* __restrict__ off,
                                               const int* __restrict__ bsum,
                                               int nbk, int n, int E) {
  __shared__ int sadd;
  const int t = threadIdx.x;
  if (t < 64) {
    int v = (t < nbk && t < (int)blockIdx.x) ? bsum[t] : 0;
    #pragma unroll
    for (int msk = 1; msk < 64; msk <<= 1) v += __shfl_xor(v, msk);
    if (t == 0) sadd = v;
  }
  __syncthreads();
  int add = sadd;
  int base = blockIdx.x * SC_EPB + t * 4;
  if (base + 3 < n) {
    int4 v = *reinterpret_cast<int4*>(off + base);
    v.x += add; v.y += add; v.z += add; v.w += add;
    *reinterpret_cast<int4*>(off + base) = v;
  } else {
    if (base     < n) off[base]     += add;
    if (base + 1 < n) off[base + 1] += add;
    if (base + 2 < n) off[base + 2] += add;
  }
  if (blockIdx.x == 0 && t == 0) off[n] = E;
}

__global__ void k_scatter(const int* __restrict__ src, const int* __restrict__ dst,
                          const int* __restrict__ off, int* __restrict__ cur,
                          int* __restrict__ csr, int E) {
  int e = blockIdx.x * blockDim.x + threadIdx.x;
  if (e < E) {
    int d = dst[e];
    int p = off[d] + atomicAdd(&cur[d], 1);
    csr[p] = src[e];
  }
}

// =====================================================================
// k_mmT: one-tile-per-block GEMM for K=128 (round-8 proven). 512 thr,
// 8 waves (2x4 of 64x32). FLAGS: 1=bias 2=relu 4=res 8=LN(gridx==1)
// =====================================================================
template<int FLAGS, bool QKVSPLIT, bool OUTF, bool OUTB>
__global__ __launch_bounds__(512, 2) void k_mmT(
    const ushort* __restrict__ A, const ushort* __restrict__ W,
    const float* __restrict__ bias, const float* __restrict__ res,
    const float* __restrict__ lng, const float* __restrict__ lnbv,
    float* __restrict__ Cf, ushort* __restrict__ Cb, ushort* __restrict__ Cb2,
    int M, int ldc)
{
  __shared__ ushort As[128 * 128];
  __shared__ ushort Bs[128 * 128];
  __shared__ float lnred[(FLAGS & 8) ? 1024 : 4];

  const int tid = threadIdx.x;
  const int wv = tid >> 6, ln = tid & 63;
  const int bnb = blockIdx.x;
  const int mbase = blockIdx.y * 128;
  const int wrow = (wv >> 2) * 64, wcol = (wv & 3) * 32;
  const int o_base = tid * 16;

  #pragma unroll
  for (int is = 0; is < 4; ++is) {
    int o = is * 8192 + o_base;
    int row = o >> 8;
    int c = ((o >> 4) & 15) ^ (row & 15);
    int gr = min(mbase + row, M - 1);
    const ushort* sA = A + (size_t)gr * 128 + c * 8;
    __builtin_amdgcn_global_load_lds(
        (const __attribute__((address_space(1))) void*)sA,
        (__attribute__((address_space(3))) void*)((char*)As + is * 8192 + wv * 1024),
        16, 0, 0);
    const ushort* sB = W + (size_t)(bnb * 128 + row) * 128 + c * 8;
    __builtin_amdgcn_global_load_lds(
        (const __attribute__((address_space(1))) void*)sB,
        (__attribute__((address_space(3))) void*)((char*)Bs + is * 8192 + wv * 1024),
        16, 0, 0);
  }
  __syncthreads();

  f32x4 acc[4][2] = {};
  const char* AsB = (const char*)As;
  const char* BsB = (const char*)Bs;
  #pragma unroll
  for (int kk = 0; kk < 4; ++kk) {
    bf16x8 af[4], bfr[2];
    #pragma unroll
    for (int m = 0; m < 4; ++m) {
      int r = wrow + m * 16 + (ln & 15);
      int c = kk * 4 + (ln >> 4);
      af[m] = *reinterpret_cast<const bf16x8*>(AsB + r * 256 + ((c ^ (r & 15)) << 4));
    }
    #pragma unroll
    for (int n = 0; n < 2; ++n) {
      int r = wcol + n * 16 + (ln & 15);
      int c = kk * 4 + (ln >> 4);
      bfr[n] = *reinterpret_cast<const bf16x8*>(BsB + r * 256 + ((c ^ (r & 15)) << 4));
    }
    #pragma unroll
    for (int m = 0; m < 4; ++m)
      #pragma unroll
      for (int n = 0; n < 2; ++n)
        acc[m][n] = __builtin_amdgcn_mfma_f32_16x16x32_bf16(af[m], bfr[n], acc[m][n], 0, 0, 0);
  }

  if constexpr ((FLAGS & 8) != 0) {
    #pragma unroll
    for (int m = 0; m < 4; ++m)
      #pragma unroll
      for (int n = 0; n < 2; ++n) {
        int gc = wcol + n * 16 + (ln & 15);
        #pragma unroll
        for (int r = 0; r < 4; ++r) {
          int gr = mbase + wrow + m * 16 + (ln >> 4) * 4 + r;
          float v = acc[m][n][r];
          if (FLAGS & 1) v += bias[gc];
          if (FLAGS & 2) v = fmaxf(v, 0.f);
          if (FLAGS & 4) v += res[(size_t)min(gr, M - 1) * 128 + gc];
          acc[m][n][r] = v;
        }
      }
    #pragma unroll
    for (int m = 0; m < 4; ++m)
      #pragma unroll
      for (int r = 0; r < 4; ++r) {
        float sm = acc[m][0][r] + acc[m][1][r];
        float sq = acc[m][0][r] * acc[m][0][r] + acc[m][1][r] * acc[m][1][r];
        #pragma unroll
        for (int msk = 1; msk <= 8; msk <<= 1) {
          sm += __shfl_xor(sm, msk);
          sq += __shfl_xor(sq, msk);
        }
        if ((ln & 15) == 0) {
          int row = wrow + m * 16 + (ln >> 4) * 4 + r;
          lnred[row * 8 + (wv & 3) * 2]     = sm;
          lnred[row * 8 + (wv & 3) * 2 + 1] = sq;
        }
      }
    __syncthreads();
    #pragma unroll
    for (int m = 0; m < 4; ++m)
      #pragma unroll
      for (int r = 0; r < 4; ++r) {
        int row = wrow + m * 16 + (ln >> 4) * 4 + r;
        int gr = mbase + row;
        float sm = lnred[row * 8] + lnred[row * 8 + 2] + lnred[row * 8 + 4] + lnred[row * 8 + 6];
        float sq = lnred[row * 8 + 1] + lnred[row * 8 + 3] + lnred[row * 8 + 5] + lnred[row * 8 + 7];
        float mu = sm * (1.f / 128.f);
        float var = fmaxf(sq * (1.f / 128.f) - mu * mu, 0.f);
        float rstd = rsqrtf(var + LN_EPS);
        if (gr < M) {
          #pragma unroll
          for (int n = 0; n < 2; ++n) {
            int gc = wcol + n * 16 + (ln & 15);
            float y = (acc[m][n][r] - mu) * rstd * lng[gc] + lnbv[gc];
            if (OUTF) Cf[(size_t)gr * 128 + gc] = y;
            if (OUTB) Cb[(size_t)gr * 128 + gc] = f2b(y);
          }
        }
      }
  } else {
    #pragma unroll
    for (int m = 0; m < 4; ++m) {
      int gr0 = mbase + wrow + m * 16 + (ln >> 4) * 4;
      #pragma unroll
      for (int n = 0; n < 2; ++n) {
        int gcl = wcol + n * 16 + (ln & 15);
        float bsv = (FLAGS & 1) ? bias[bnb * 128 + gcl] : 0.f;
        #pragma unroll
        for (int r = 0; r < 4; ++r) {
          int gr = gr0 + r;
          if (gr >= M) continue;
          float v = acc[m][n][r] + bsv;
          if (FLAGS & 2) v = fmaxf(v, 0.f);
          if (QKVSPLIT) {
            if (bnb == 0) Cb[(size_t)gr * 128 + gcl] = f2b(v);
            else          Cb2[(size_t)gr * 256 + (bnb - 1) * 128 + gcl] = f2b(v);
          } else {
            if (OUTF) Cf[(size_t)gr * ldc + bnb * 128 + gcl] = v;
            if (OUTB) Cb[(size_t)gr * ldc + bnb * 128 + gcl] = f2b(v);
          }
        }
      }
    }
  }
}

// =====================================================================
// k_ffn: fused FFN, all operands LDS-staged, double-buffered W tiles.
// 512 thr / 8 waves; 64 rows per block. LDS = mid 64KB + wbuf 2x32KB.
// Ph1: 4 W1 row-groups [128][128] dbuf; p1[g][hj] static-indexed.
// Ph2: 4 W2 k-slices [128][128] dbuf. lnred aliases wbuf.
// =====================================================================
__global__ __launch_bounds__(512, 2) void k_ffn(
    const ushort* __restrict__ h1b, const float* __restrict__ h1f,
    const ushort* __restrict__ w1, const float* __restrict__ b1,
    const ushort* __restrict__ w2, const float* __restrict__ b2,
    const float* __restrict__ lng, const float* __restrict__ lnbv,
    float* __restrict__ outp, int M)
{
  __shared__ ushort mid[64 * 512];        // 64KB: rows of 1024B, 16B-chunk XOR swizzle
  __shared__ ushort wbuf[2][128 * 128];   // 2 x 32KB: [128][256B] k_mmT idiom

  const int tid = threadIdx.x;
  const int wv = tid >> 6, ln = tid & 63;
  const int lr = ln & 15, hi = ln >> 4;
  const int mbase = blockIdx.x * 64;

  auto STG128 = [&](const ushort* srcBase, int srcLd, int colOff, ushort* dstLds) {
    #pragma unroll
    for (int is = 0; is < 4; ++is) {
      int o = is * 8192 + tid * 16;
      int r = o >> 8;
      int c = ((o >> 4) & 15) ^ (r & 15);
      const ushort* s = srcBase + (size_t)r * srcLd + colOff + c * 8;
      __builtin_amdgcn_global_load_lds(
          (const __attribute__((address_space(1))) void*)s,
          (__attribute__((address_space(3))) void*)((char*)dstLds + is * 8192 + wv * 1024),
          16, 0, 0);
    }
  };

  // ---- prologue: stage h1b tile [64][128] into mid[0:16KB] + W1 group 0 ----
  #pragma unroll
  for (int is = 0; is < 2; ++is) {
    int o = is * 8192 + tid * 16;
    int r = o >> 8;
    int c = ((o >> 4) & 15) ^ (r & 15);
    int gr = min(mbase + r, M - 1);
    const ushort* s = h1b + (size_t)gr * 128 + c * 8;
    __builtin_amdgcn_global_load_lds(
        (const __attribute__((address_space(1))) void*)s,
        (__attribute__((address_space(3))) void*)((char*)mid + is * 8192 + wv * 1024),
        16, 0, 0);
  }
  STG128(w1, 128, 0, wbuf[0]);
  __syncthreads();

  // ---- phase 1: p1[g][hj] = mfma(W1rows, h1rows); wave owns mid cols g*128+wv*16..+16 ----
  f32x4 p1[4][4] = {};
  const char* hB = (const char*)mid;
  #pragma unroll
  for (int g = 0; g < 4; ++g) {
    const int buf = g & 1;
    if (g < 3) STG128(w1 + (size_t)(g + 1) * 128 * 128, 128, 0, wbuf[buf ^ 1]);
    else       STG128(w2, 512, 0, wbuf[buf ^ 1]);   // W2 k-slice 0, used in ph2
    const char* wB = (const char*)wbuf[buf];
    #pragma unroll
    for (int kk = 0; kk < 4; ++kk) {
      int c = kk * 4 + hi;
      int wr = wv * 16 + lr;
      bf16x8 aW = *reinterpret_cast<const bf16x8*>(wB + wr * 256 + ((c ^ (wr & 15)) << 4));
      bf16x8 bH[4];
      #pragma unroll
      for (int hj = 0; hj < 4; ++hj) {
        int r = hj * 16 + lr;
        bH[hj] = *reinterpret_cast<const bf16x8*>(hB + r * 256 + ((c ^ (r & 15)) << 4));
      }
      #pragma unroll
      for (int hj = 0; hj < 4; ++hj)
        p1[g][hj] = __builtin_amdgcn_mfma_f32_16x16x32_bf16(aW, bH[hj], p1[g][hj], 0, 0, 0);
    }
    __syncthreads();
  }

  // ---- write mid: [64][512] bf16, 64-chunk XOR swizzle; h1b region now dead ----
  #pragma unroll
  for (int g = 0; g < 4; ++g) {
    int mc0 = g * 128 + wv * 16 + hi * 4;           // 4 consecutive mid cols
    float4 bv = *reinterpret_cast<const float4*>(b1 + mc0);
    int chunk = mc0 >> 3;
    int sub = (mc0 & 7) * 2;                        // 0 or 8 bytes
    #pragma unroll
    for (int hj = 0; hj < 4; ++hj) {
      int orow = hj * 16 + lr;
      ushort4 pk;
      pk.x = f2b(fmaxf(p1[g][hj][0] + bv.x, 0.f));
      pk.y = f2b(fmaxf(p1[g][hj][1] + bv.y, 0.f));
      pk.z = f2b(fmaxf(p1[g][hj][2] + bv.z, 0.f));
      pk.w = f2b(fmaxf(p1[g][hj][3] + bv.w, 0.f));
      char* dstp = (char*)mid + orow * 1024 + (((chunk & 63) ^ (orow & 15)) << 4) + sub;
      *reinterpret_cast<ushort4*>(dstp) = pk;
    }
  }
  __syncthreads();

  // ---- phase 2: p2 = mid @ W2^T; wave owns out cols wv*16..+16 ----
  f32x4 p2[4] = {};
  #pragma unroll
  for (int g2 = 0; g2 < 4; ++g2) {
    const int buf = g2 & 1;
    if (g2 < 3) STG128(w2, 512, (g2 + 1) * 128, wbuf[buf ^ 1]);
    const char* wB = (const char*)wbuf[buf];
    #pragma unroll
    for (int kk = 0; kk < 4; ++kk) {
      int wr = wv * 16 + lr;
      int cw = kk * 4 + hi;
      bf16x8 bW = *reinterpret_cast<const bf16x8*>(wB + wr * 256 + ((cw ^ (wr & 15)) << 4));
      int cm = g2 * 16 + kk * 4 + hi;               // logical 16B chunk in mid row
      bf16x8 aM[4];
      #pragma unroll
      for (int m = 0; m < 4; ++m) {
        int r = m * 16 + lr;
        aM[m] = *reinterpret_cast<const bf16x8*>((const char*)mid + r * 1024 + (((cm & 63) ^ (r & 15)) << 4));
      }
      #pragma unroll
      for (int m = 0; m < 4; ++m)
        p2[m] = __builtin_amdgcn_mfma_f32_16x16x32_bf16(aM[m], bW, p2[m], 0, 0, 0);
    }
    __syncthreads();
  }

  // ---- LN2 epilogue (lnred aliases wbuf; all wbuf reads complete) ----
  float* lnred = reinterpret_cast<float*>(&wbuf[0][0]);
  {
    int gc = wv * 16 + lr;
    float bsv = b2[gc];
    #pragma unroll
    for (int m = 0; m < 4; ++m)
      #pragma unroll
      for (int r = 0; r < 4; ++r) {
        int gr = mbase + m * 16 + hi * 4 + r;
        p2[m][r] += bsv + h1f[(size_t)min(gr, M - 1) * 128 + gc];
      }
  }
  #pragma unroll
  for (int m = 0; m < 4; ++m)
    #pragma unroll
    for (int r = 0; r < 4; ++r) {
      float sm = p2[m][r];
      float sq = p2[m][r] * p2[m][r];
      #pragma unroll
      for (int msk = 1; msk <= 8; msk <<= 1) {
        sm += __shfl_xor(sm, msk);
        sq += __shfl_xor(sq, msk);
      }
      if (lr == 0) {
        int row = m * 16 + hi * 4 + r;
        lnred[row * 16 + wv * 2]     = sm;
        lnred[row * 16 + wv * 2 + 1] = sq;
      }
    }
  __syncthreads();
  #pragma unroll
  for (int m = 0; m < 4; ++m)
    #pragma unroll
    for (int r = 0; r < 4; ++r) {
      int row = m * 16 + hi * 4 + r;
      int gr = mbase + row;
      float sm = 0.f, sq = 0.f;
      #pragma unroll
      for (int w = 0; w < 8; ++w) {
        sm += lnred[row * 16 + w * 2];
        sq += lnred[row * 16 + w * 2 + 1];
      }
      float mu = sm * (1.f / 128.f);
      float var = fmaxf(sq * (1.f / 128.f) - mu * mu, 0.f);
      float rstd = rsqrtf(var + LN_EPS);
      if (gr < M) {
        int gc = wv * 16 + lr;
        outp[(size_t)gr * 128 + gc] = (p2[m][r] - mu) * rstd * lng[gc] + lnbv[gc];
      }
    }
}

// ---------------- edge-softmax attention (round-7 proven: fixed-max) ----
__global__ __launch_bounds__(256) void k_attn(
    const ushort* __restrict__ q, const ushort* __restrict__ kv,
    const int* __restrict__ off, const int* __restrict__ csr,
    ushort* __restrict__ sav, int n)
{
  int node = blockIdx.x * 4 + (threadIdx.x >> 6);
  int lane = threadIdx.x & 63;
  if (node >= n) return;
  const int g = lane >> 3, sl = lane & 7;

  const ushort* qr = q + (size_t)node * 128 + sl * 16;
  uint4 qw0 = *reinterpret_cast<const uint4*>(qr);
  uint4 qw1 = *reinterpret_cast<const uint4*>(qr + 8);
  float qv[16];
  unpack8w(qw0, qv); unpack8w(qw1, qv + 8);

  int b = off[node], e = off[node + 1];
  float s = 0.f;
  float a[16] = {};
  int nIt = (e - b + 7) >> 3;
  int idx = b + g;
  int sn = (b < e) ? csr[min(idx, e - 1)] : 0;

  for (int i = 0; i < nIt; ++i) {
    bool act = idx < e;
    const ushort* kr = kv + (size_t)sn * 256 + sl * 16;
    uint4 kw0 = *reinterpret_cast<const uint4*>(kr);
    uint4 kw1 = *reinterpret_cast<const uint4*>(kr + 8);
    uint4 vw0 = *reinterpret_cast<const uint4*>(kr + 128);
    uint4 vw1 = *reinterpret_cast<const uint4*>(kr + 136);
    idx += 8;
    if (i + 1 < nIt) sn = csr[min(idx, e - 1)];

    float kk[16];
    unpack8w(kw0, kk); unpack8w(kw1, kk + 8);
    float p = 0.f;
    #pragma unroll
    for (int j = 0; j < 16; ++j) p = fmaf(qv[j], kk[j], p);
    float u = fminf(fmaxf(p * 0.25f, -CLAMP_V), CLAMP_V);
    float w = __expf(u - CLAMP_V);
    w = act ? w : 0.f;
    s += w;
    float vvv[16];
    unpack8w(vw0, vvv); unpack8w(vw1, vvv + 8);
    #pragma unroll
    for (int j = 0; j < 16; ++j) a[j] = fmaf(w, vvv[j], a[j]);
  }

  #pragma unroll
  for (int msk = 8; msk <= 32; msk <<= 1) {
    s += __shfl_xor(s, msk);
    #pragma unroll
    for (int j = 0; j < 16; ++j) a[j] += __shfl_xor(a[j], msk);
  }

  float inv = (s > 0.f) ? 1.f / s : 0.f;
  if (g == 0) {
    uint w[8];
    #pragma unroll
    for (int j = 0; j < 8; ++j)
      w[j] = (uint)f2b(a[2 * j] * inv) | ((uint)f2b(a[2 * j + 1] * inv) << 16);
    ushort* outp = sav + (size_t)node * 128 + sl * 16;
    uint4 o0 = {w[0], w[1], w[2], w[3]};
    uint4 o1 = {w[4], w[5], w[6], w[7]};
    *reinterpret_cast<uint4*>(outp) = o0;
    *reinterpret_cast<uint4*>(outp + 8) = o1;
  }
}

extern "C" void kernel_launch(void* const* d_in, const int* in_sizes, int n_in,
                              void* d_out, int out_size, void* d_ws, size_t ws_size,
                              hipStream_t stream)
{
  const float* feat = (const float*)d_in[0];
  const int*   src  = (const int*)d_in[1];
  const int*   dst  = (const int*)d_in[2];
  const float* Wq   = (const float*)d_in[3];
  const float* Wk   = (const float*)d_in[4];
  const float* Wv   = (const float*)d_in[5];
  const float* Wo   = (const float*)d_in[6];
  const float* ln1g = (const float*)d_in[7];
  const float* ln1b = (const float*)d_in[8];
  const float* W1   = (const float*)d_in[9];
  const float* b1   = (const float*)d_in[10];
  const float* W2   = (const float*)d_in[11];
  const float* b2   = (const float*)d_in[12];
  const float* ln2g = (const float*)d_in[13];
  const float* ln2b = (const float*)d_in[14];
  float* out = (float*)d_out;

  const int N = in_sizes[0] / DM;
  const int E = in_sizes[1];
  const size_t NB = (size_t)N;

  char* wsb = (char*)d_ws;
  ushort* q_bf    = (ushort*)wsb;
  ushort* kv_bf   = (ushort*)(wsb + NB * 256);
  ushort* sav_bf  = (ushort*)(wsb + NB * 768);
  float*  h1      = (float*)(wsb + NB * 1024);
  ushort* h1b     = (ushort*)(wsb + NB * 1536);
  ushort* feat_bf = (ushort*)(wsb + NB * 1792);
  ushort* wbf     = (ushort*)(wsb + NB * 2048);
  ushort* wqkv_bf = wbf;
  ushort* wo_bf   = wbf + 49152;
  ushort* w1_bf   = wbf + 65536;
  ushort* w2_bf   = wbf + 131072;
  int* ib  = (int*)(wbf + 196608);
  int* deg = ib;
  int* cur = ib + N;
  int* off = ib + 2 * N;
  int* csr = ib + 3 * N + 1;
  int* bsum = csr + E;

  hipMemsetAsync(deg, 0, 2 * (size_t)N * sizeof(int), stream);

  int nf4 = N * DM / 4;
  int castBlocks = (nf4 + 49152 + 255) / 256;
  int cntBlocks = (E + 255) / 256;
  k_prep<<<castBlocks + cntBlocks, 256, 0, stream>>>(
      feat, Wq, Wk, Wv, Wo, W1, W2, feat_bf, wbf, dst, deg, nf4, castBlocks, E);

  int nbk = (N + SC_EPB - 1) / SC_EPB;
  k_scan1<<<nbk, 256, 0, stream>>>(deg, off, bsum, N);
  k_scan3<<<nbk, 256, 0, stream>>>(off, bsum, nbk, N, E);
  k_scatter<<<cntBlocks, 256, 0, stream>>>(src, dst, off, cur, csr, E);

  int nb4 = (N + 3) / 4;
  const int nT = (N + 127) / 128;   // 313

  // qkv: grid (3, nT), split output q_bf | kv_bf
  k_mmT<0, true, false, true><<<dim3(3, nT), 512, 0, stream>>>(
      feat_bf, wqkv_bf, nullptr, nullptr, nullptr, nullptr,
      nullptr, q_bf, kv_bf, N, 128);

  k_attn<<<nb4, 256, 0, stream>>>(q_bf, kv_bf, off, csr, sav_bf, N);

  // h1 = LN1(sav @ Wo^T + feat) -> h1 f32 + h1b bf16
  k_mmT<4 | 8, false, true, true><<<dim3(1, nT), 512, 0, stream>>>(
      sav_bf, wo_bf, nullptr, feat, ln1g, ln1b, h1, h1b, nullptr, N, 128);

  // fused FFN: out = LN2(relu(h1b@W1^T+b1)@W2^T + b2 + h1)
  const int nF = (N + 63) / 64;     // 625
  k_ffn<<<nF, 512, 0, stream>>>(
      h1b, h1, w1_bf, b1, w2_bf, b2, ln2g, ln2b, out, N);
}